// Round 8
// baseline (800.162 us; speedup 1.0000x reference)
//
#include <hip/hip_runtime.h>

// Static float4 component access (folds to .x/.y/.z/.w after unroll).
#define F4E(v,i) ((i)==0?(v).x:((i)==1?(v).y:((i)==2?(v).z:(v).w)))

#define CHUNK 4096      // edges per partition block (512 threads x 8)
#define ITERS 8

__device__ inline float4 shfl4b(float4 v, int src) {
    float4 r;
    r.x = __shfl(v.x, src, 4); r.y = __shfl(v.y, src, 4);
    r.z = __shfl(v.z, src, 4); r.w = __shfl(v.w, src, 4);
    return r;
}
__device__ inline float4 shfl8b(float4 v, int src) {
    float4 r;
    r.x = __shfl(v.x, src, 8); r.y = __shfl(v.y, src, 8);
    r.z = __shfl(v.z, src, 8); r.w = __shfl(v.w, src, 8);
    return r;
}

// ---------------------------------------------------------------------------
// Bucket histogram: bucket = dst >> 8 (256 nodes per bucket), NB <= 512.
__global__ __launch_bounds__(512) void k_bhist(
    const int* __restrict__ ei, int* __restrict__ bhist, int E, int NB)
{
    __shared__ int cnt[512];
    int t = threadIdx.x;
    cnt[t] = 0;
    __syncthreads();
    int base = blockIdx.x * CHUNK;
#pragma unroll
    for (int i = 0; i < ITERS; ++i) {
        int e = base + i * 512 + t;
        if (e < E) {
            int dst = ei[E + e];
            atomicAdd(&cnt[dst >> 8], 1);
        }
    }
    __syncthreads();
    if (t < NB && cnt[t]) atomicAdd(&bhist[t], cnt[t]);
}

// Exclusive scan of bucket counts (NB <= 512), writes bstart + cursor init.
__global__ __launch_bounds__(512) void k_bscan(
    const int* __restrict__ bhist, int* __restrict__ bstart,
    int* __restrict__ gcursor, int NB, int E)
{
    __shared__ int s[512];
    int t = threadIdx.x;
    int v0 = (t < NB) ? bhist[t] : 0;
    s[t] = v0;
    __syncthreads();
    for (int off = 1; off < 512; off <<= 1) {
        int v = (t >= off) ? s[t - off] : 0;
        __syncthreads();
        s[t] += v;
        __syncthreads();
    }
    if (t < NB) { int ex = s[t] - v0; bstart[t] = ex; gcursor[t] = ex; }
    if (t == 0) bstart[NB] = E;
}

// Partition edges into bucket-contiguous packed list, coalesced flush.
// packed = (src << 8) | (dst & 255); requires N < 2^17 (holds: 100000).
__global__ __launch_bounds__(512) void k_partition(
    const int* __restrict__ ei, int* __restrict__ gcursor,
    int* __restrict__ epack, int E)
{
    __shared__ int cnt[512], sc[512], lbase[512], gbase[512], lcnt[512];
    __shared__ int stage[CHUNK];
    __shared__ unsigned short stageb[CHUNK];
    int t = threadIdx.x;
    cnt[t] = 0; lcnt[t] = 0;
    __syncthreads();

    int base = blockIdx.x * CHUNK;
    int pk[ITERS], bb[ITERS];
#pragma unroll
    for (int i = 0; i < ITERS; ++i) {
        int e = base + i * 512 + t;
        if (e < E) {
            int src = ei[e], dst = ei[E + e];
            pk[i] = (src << 8) | (dst & 255);
            bb[i] = dst >> 8;
            atomicAdd(&cnt[bb[i]], 1);
        } else bb[i] = -1;
    }
    __syncthreads();

    int v0 = cnt[t];
    sc[t] = v0;
    __syncthreads();
    for (int off = 1; off < 512; off <<= 1) {
        int v = (t >= off) ? sc[t - off] : 0;
        __syncthreads();
        sc[t] += v;
        __syncthreads();
    }
    lbase[t] = sc[t] - v0;
    if (v0 > 0) gbase[t] = atomicAdd(&gcursor[t], v0);
    __syncthreads();

#pragma unroll
    for (int i = 0; i < ITERS; ++i) {
        if (bb[i] >= 0) {
            int loc = atomicAdd(&lcnt[bb[i]], 1);
            int slot = lbase[bb[i]] + loc;
            stage[slot] = pk[i];
            stageb[slot] = (unsigned short)bb[i];
        }
    }
    __syncthreads();

    int m = min(CHUNK, E - base);
#pragma unroll
    for (int i = 0; i < ITERS; ++i) {
        int slot = i * 512 + t;
        if (slot < m) {
            int b = stageb[slot];
            epack[gbase[b] + (slot - lbase[b])] = stage[slot];
        }
    }
}

// ---------------------------------------------------------------------------
// Per-bucket counting sort by dst&255 -> per-node CSR (rs + esorted of src).
// Also accumulates the 64-bin global degree histogram for k_perm.
__global__ __launch_bounds__(256) void k_sort(
    const int* __restrict__ bstart, const int* __restrict__ epack,
    int* __restrict__ rs, int* __restrict__ esorted,
    int* __restrict__ dcnt, int N, int E)
{
    __shared__ int hist[256], cur[256], sc[256];
    int t = threadIdx.x;
    int b = blockIdx.x;
    int s0 = bstart[b], s1 = bstart[b + 1];
    hist[t] = 0;
    __syncthreads();
    for (int e = s0 + t; e < s1; e += 256)
        atomicAdd(&hist[epack[e] & 255], 1);
    __syncthreads();

    int v0 = hist[t];
    sc[t] = v0;
    __syncthreads();
    for (int off = 1; off < 256; off <<= 1) {
        int v = (t >= off) ? sc[t - off] : 0;
        __syncthreads();
        sc[t] += v;
        __syncthreads();
    }
    int excl = sc[t] - v0;
    cur[t] = excl;
    int node = (b << 8) + t;
    if (node < N) {
        rs[node] = s0 + excl;
        atomicAdd(&dcnt[min(v0, 63)], 1);   // degree histogram
    }
    if (b == 0 && t == 0) rs[N] = E;
    __syncthreads();

    for (int e = s0 + t; e < s1; e += 256) {
        int pk = epack[e];
        int dlo = pk & 255;
        int pos = s0 + atomicAdd(&cur[dlo], 1);
        esorted[pos] = ((unsigned)pk) >> 8;
    }
}

// ---------------------------------------------------------------------------
// Degree-binned node permutation: nodes sorted by (clamped) degree so that
// nodes sharing a wave in the gather kernels have ~equal edge counts.
__global__ __launch_bounds__(256) void k_perm(
    const int* __restrict__ rs, const int* __restrict__ dcnt,
    int* __restrict__ dcur, int* __restrict__ perm, int N)
{
    __shared__ int sstart[64];
    int t = threadIdx.x;
    if (t < 64) {                        // wave 0: shfl-scan of 64 bins
        int v = dcnt[t];
        int incl = v;
#pragma unroll
        for (int d = 1; d < 64; d <<= 1) {
            int o = __shfl_up(incl, d, 64);
            if (t >= d) incl += o;
        }
        sstart[t] = incl - v;
    }
    __syncthreads();
    int node = blockIdx.x * 256 + t;
    if (node >= N) return;
    int deg = rs[node + 1] - rs[node];
    int bin = min(deg, 63);
    int pos = sstart[bin] + atomicAdd(&dcur[bin], 1);
    perm[pos] = node;
}

// ---------------------------------------------------------------------------
// Fused gather(F=16) + layer1: 4 threads per node, degree-binned order.
__global__ __launch_bounds__(256) void k_g1f(
    const float* __restrict__ x, const int* __restrict__ rs,
    const int* __restrict__ esrc, const int* __restrict__ perm,
    const float* __restrict__ wroot, const float* __restrict__ wrel,
    const float* __restrict__ bias, float* __restrict__ h1, int N)
{
    __shared__ float4 s_wr[128], s_wl[128], s_b[8];   // 16x32 each, bias 32
    int t = threadIdx.x;
    if (t < 128) {
        s_wr[t] = reinterpret_cast<const float4*>(wroot)[t];
        s_wl[t] = reinterpret_cast<const float4*>(wrel)[t];
    }
    if (t < 8) s_b[t] = reinterpret_cast<const float4*>(bias)[t];
    __syncthreads();

    int tid = blockIdx.x * 256 + t;
    int q = tid >> 2, p = tid & 3;
    if (q >= N) return;
    int n = perm[q];
    int s0 = rs[n], s1 = rs[n + 1];
    float4 g = make_float4(0.f, 0.f, 0.f, 0.f);
    int e = s0;
    for (; e + 3 < s1; e += 4) {
        int sa = esrc[e], sb = esrc[e + 1], sc = esrc[e + 2], sd = esrc[e + 3];
        float4 v0 = *reinterpret_cast<const float4*>(x + (size_t)sa * 16 + p * 4);
        float4 v1 = *reinterpret_cast<const float4*>(x + (size_t)sb * 16 + p * 4);
        float4 v2 = *reinterpret_cast<const float4*>(x + (size_t)sc * 16 + p * 4);
        float4 v3 = *reinterpret_cast<const float4*>(x + (size_t)sd * 16 + p * 4);
        g.x += (v0.x + v1.x) + (v2.x + v3.x);
        g.y += (v0.y + v1.y) + (v2.y + v3.y);
        g.z += (v0.z + v1.z) + (v2.z + v3.z);
        g.w += (v0.w + v1.w) + (v2.w + v3.w);
    }
    for (; e < s1; ++e) {
        int sa = esrc[e];
        float4 v0 = *reinterpret_cast<const float4*>(x + (size_t)sa * 16 + p * 4);
        g.x += v0.x; g.y += v0.y; g.z += v0.z; g.w += v0.w;
    }
    float4 a = *reinterpret_cast<const float4*>(x + (size_t)n * 16 + p * 4);

    int jb = p * 2;                          // my 2 float4 columns of 8
    float4 acc0 = s_b[jb], acc1 = s_b[jb + 1];
#pragma unroll
    for (int kc = 0; kc < 4; ++kc) {
        float4 a4 = shfl4b(a, kc);
        float4 g4 = shfl4b(g, kc);
#pragma unroll
        for (int kk = 0; kk < 4; ++kk) {
            float av = F4E(a4, kk), gv = F4E(g4, kk);
            int k = kc * 4 + kk;
            float4 wr0 = s_wr[k * 8 + jb], wr1 = s_wr[k * 8 + jb + 1];
            float4 wl0 = s_wl[k * 8 + jb], wl1 = s_wl[k * 8 + jb + 1];
            acc0.x += av * wr0.x + gv * wl0.x;
            acc0.y += av * wr0.y + gv * wl0.y;
            acc0.z += av * wr0.z + gv * wl0.z;
            acc0.w += av * wr0.w + gv * wl0.w;
            acc1.x += av * wr1.x + gv * wl1.x;
            acc1.y += av * wr1.y + gv * wl1.y;
            acc1.z += av * wr1.z + gv * wl1.z;
            acc1.w += av * wr1.w + gv * wl1.w;
        }
    }
    acc0.x = fmaxf(acc0.x, 0.f); acc0.y = fmaxf(acc0.y, 0.f);
    acc0.z = fmaxf(acc0.z, 0.f); acc0.w = fmaxf(acc0.w, 0.f);
    acc1.x = fmaxf(acc1.x, 0.f); acc1.y = fmaxf(acc1.y, 0.f);
    acc1.z = fmaxf(acc1.z, 0.f); acc1.w = fmaxf(acc1.w, 0.f);
    float4* o = reinterpret_cast<float4*>(h1 + (size_t)n * 32 + p * 8);
    o[0] = acc0; o[1] = acc1;
}

// ---------------------------------------------------------------------------
// Fused gather(F=32) + layer2 + fc1 + fc2: 8 threads per node,
// degree-binned order. Writes final output directly.
__global__ __launch_bounds__(256) void k_g2f(
    const float* __restrict__ h1, const int* __restrict__ rs,
    const int* __restrict__ esrc, const int* __restrict__ perm,
    const float* __restrict__ wroot, const float* __restrict__ wrel,
    const float* __restrict__ bias,
    const float* __restrict__ f1w, const float* __restrict__ f1b,
    const float* __restrict__ f2w, const float* __restrict__ f2b,
    float* __restrict__ out, int N)
{
    __shared__ float4 s_wr[512], s_wl[512], s_b[16];  // 32x64 weights, bias 64
    __shared__ float4 s_f1[512];                      // 64x32, jc-swizzled
    __shared__ float  s_f2[512];                      // 32x16
    __shared__ float4 s_b1[8];
    __shared__ float  s_b2[16];
    int t = threadIdx.x;
    for (int i = t; i < 512; i += 256) {
        s_wr[i] = reinterpret_cast<const float4*>(wroot)[i];
        s_wl[i] = reinterpret_cast<const float4*>(wrel)[i];
        // swizzle: row k (= i>>3), col jc (= i&7) stored at jc' = (jc + (k>>3)) & 7
        // so the 8 k-split lanes (k = p*8+kk, k>>3 == p) hit 8 distinct banks.
        int k = i >> 3, jc = i & 7;
        s_f1[(i & ~7) | ((jc + (k >> 3)) & 7)] = reinterpret_cast<const float4*>(f1w)[i];
        s_f2[i] = f2w[i];
    }
    if (t < 16) s_b[t]  = reinterpret_cast<const float4*>(bias)[t];
    if (t < 8)  s_b1[t] = reinterpret_cast<const float4*>(f1b)[t];
    if (t < 16) s_b2[t] = f2b[t];
    __syncthreads();

    int tid = blockIdx.x * 256 + t;
    int q = tid >> 3, p = tid & 7;
    if (q >= N) return;
    int n = perm[q];

    // gather my float4 slice of agg2 (4 loads in flight)
    int s0 = rs[n], s1 = rs[n + 1];
    float4 g = make_float4(0.f, 0.f, 0.f, 0.f);
    int e = s0;
    for (; e + 3 < s1; e += 4) {
        int sa = esrc[e], sb = esrc[e + 1], sc = esrc[e + 2], sd = esrc[e + 3];
        float4 v0 = *reinterpret_cast<const float4*>(h1 + (size_t)sa * 32 + p * 4);
        float4 v1 = *reinterpret_cast<const float4*>(h1 + (size_t)sb * 32 + p * 4);
        float4 v2 = *reinterpret_cast<const float4*>(h1 + (size_t)sc * 32 + p * 4);
        float4 v3 = *reinterpret_cast<const float4*>(h1 + (size_t)sd * 32 + p * 4);
        g.x += (v0.x + v1.x) + (v2.x + v3.x);
        g.y += (v0.y + v1.y) + (v2.y + v3.y);
        g.z += (v0.z + v1.z) + (v2.z + v3.z);
        g.w += (v0.w + v1.w) + (v2.w + v3.w);
    }
    for (; e < s1; ++e) {
        int sa = esrc[e];
        float4 v0 = *reinterpret_cast<const float4*>(h1 + (size_t)sa * 32 + p * 4);
        g.x += v0.x; g.y += v0.y; g.z += v0.z; g.w += v0.w;
    }
    float4 a = *reinterpret_cast<const float4*>(h1 + (size_t)n * 32 + p * 4);

    // layer2: my 8 of 64 h2 outputs (j in [p*8, p*8+8)), jb = p*2 float4 cols
    int jb = p * 2;
    float4 acc0 = s_b[jb], acc1 = s_b[jb + 1];
#pragma unroll
    for (int kc = 0; kc < 8; ++kc) {
        float4 a4 = shfl8b(a, kc);
        float4 g4 = shfl8b(g, kc);
#pragma unroll
        for (int kk = 0; kk < 4; ++kk) {
            float av = F4E(a4, kk), gv = F4E(g4, kk);
            int k = kc * 4 + kk;
            float4 wr0 = s_wr[k * 16 + jb], wr1 = s_wr[k * 16 + jb + 1];
            float4 wl0 = s_wl[k * 16 + jb], wl1 = s_wl[k * 16 + jb + 1];
            acc0.x += av * wr0.x + gv * wl0.x;
            acc0.y += av * wr0.y + gv * wl0.y;
            acc0.z += av * wr0.z + gv * wl0.z;
            acc0.w += av * wr0.w + gv * wl0.w;
            acc1.x += av * wr1.x + gv * wl1.x;
            acc1.y += av * wr1.y + gv * wl1.y;
            acc1.z += av * wr1.z + gv * wl1.z;
            acc1.w += av * wr1.w + gv * wl1.w;
        }
    }
    acc0.x = fmaxf(acc0.x, 0.f); acc0.y = fmaxf(acc0.y, 0.f);
    acc0.z = fmaxf(acc0.z, 0.f); acc0.w = fmaxf(acc0.w, 0.f);
    acc1.x = fmaxf(acc1.x, 0.f); acc1.y = fmaxf(acc1.y, 0.f);
    acc1.z = fmaxf(acc1.z, 0.f); acc1.w = fmaxf(acc1.w, 0.f);

    // fc1 k-split: my 8 h2 values are k = p*8 + kk; partials over all 32 outs.
    // Read at swizzled slot ((jc+p)&7) -> retrieves ORIGINAL column jc;
    // accumulate into f[jc] (compile-time index) for the butterfly reduce.
    float4 f[8];
    float4 z4 = make_float4(0.f, 0.f, 0.f, 0.f);
#pragma unroll
    for (int jc = 0; jc < 8; ++jc) f[jc] = p ? z4 : s_b1[jc];
#pragma unroll
    for (int kk = 0; kk < 8; ++kk) {
        float hv = (kk < 4) ? F4E(acc0, kk) : F4E(acc1, kk - 4);
        int k = p * 8 + kk;
        int row = k * 8;
#pragma unroll
        for (int jc = 0; jc < 8; ++jc) {
            float4 w = s_f1[row | ((jc + p) & 7)];
            f[jc].x += hv * w.x; f[jc].y += hv * w.y;
            f[jc].z += hv * w.z; f[jc].w += hv * w.w;
        }
    }
    // butterfly reduce across the 8-lane group + relu
#pragma unroll
    for (int m = 1; m < 8; m <<= 1) {
#pragma unroll
        for (int jc = 0; jc < 8; ++jc) {
            f[jc].x += __shfl_xor(f[jc].x, m);
            f[jc].y += __shfl_xor(f[jc].y, m);
            f[jc].z += __shfl_xor(f[jc].z, m);
            f[jc].w += __shfl_xor(f[jc].w, m);
        }
    }
#pragma unroll
    for (int jc = 0; jc < 8; ++jc) {
        f[jc].x = fmaxf(f[jc].x, 0.f); f[jc].y = fmaxf(f[jc].y, 0.f);
        f[jc].z = fmaxf(f[jc].z, 0.f); f[jc].w = fmaxf(f[jc].w, 0.f);
    }

    // fc2 j-split: my 2 of 16 outputs (j = p*2, p*2+1).
    float o0 = s_b2[p * 2], o1 = s_b2[p * 2 + 1];
#pragma unroll
    for (int k2 = 0; k2 < 32; ++k2) {
        float av = F4E(f[k2 >> 2], k2 & 3);
        o0 += av * s_f2[k2 * 16 + p * 2];
        o1 += av * s_f2[k2 * 16 + p * 2 + 1];
    }
    float2* o = reinterpret_cast<float2*>(out + (size_t)n * 16 + p * 2);
    *o = make_float2(o0, o1);
}

// ---------------------------------------------------------------------------
extern "C" void kernel_launch(void* const* d_in, const int* in_sizes, int n_in,
                              void* d_out, int out_size, void* d_ws, size_t ws_size,
                              hipStream_t stream)
{
    const float* x   = (const float*)d_in[0];
    const int*   ei  = (const int*)d_in[1];
    const float* wr1 = (const float*)d_in[2];
    const float* wl1 = (const float*)d_in[3];
    const float* b1  = (const float*)d_in[4];
    const float* wr2 = (const float*)d_in[5];
    const float* wl2 = (const float*)d_in[6];
    const float* b2  = (const float*)d_in[7];
    const float* f1w = (const float*)d_in[8];
    const float* f1b = (const float*)d_in[9];
    const float* f2w = (const float*)d_in[10];
    const float* f2b = (const float*)d_in[11];
    float* out = (float*)d_out;

    const int N  = in_sizes[0] / 16;
    const int E  = in_sizes[1] / 2;
    const int NB = (N + 255) >> 8;      // 256 nodes per bucket, NB <= 512

    // Workspace layout (floats/ints, no aliasing; ~26.4MB of >=51.2MB):
    //   h1      : N*32 floats   12.8 MB
    //   esorted : E ints         6.4 MB
    //   epack   : E ints         6.4 MB
    //   rs      : N+1 ints
    //   [bhist NB | dcnt 64 | dcur 64]  <- single zeroing memset
    //   bstart  : NB+1 ints, gcursor : NB ints
    //   perm    : N ints
    float* ws      = (float*)d_ws;
    float* h1      = ws;
    int*   esorted = (int*)(ws + (size_t)N * 32);
    int*   epack   = esorted + E;
    int*   rs      = epack + E;
    int*   bhist   = rs + N + 1;
    int*   dcnt    = bhist + NB;
    int*   dcur    = dcnt + 64;
    int*   bstart  = dcur + 64;
    int*   gcursor = bstart + NB + 1;
    int*   perm    = gcursor + NB;

    hipMemsetAsync(bhist, 0, (size_t)(NB + 128) * sizeof(int), stream);

    int nchunk = (E + CHUNK - 1) / CHUNK;
    int g_n  = (N + 255) / 256;
    int g_g1 = (N * 4 + 255) / 256;
    int g_g2 = (N * 8 + 255) / 256;

    k_bhist    <<<nchunk, 512, 0, stream>>>(ei, bhist, E, NB);
    k_bscan    <<<1,      512, 0, stream>>>(bhist, bstart, gcursor, NB, E);
    k_partition<<<nchunk, 512, 0, stream>>>(ei, gcursor, epack, E);
    k_sort     <<<NB,     256, 0, stream>>>(bstart, epack, rs, esorted, dcnt, N, E);
    k_perm     <<<g_n,    256, 0, stream>>>(rs, dcnt, dcur, perm, N);

    k_g1f      <<<g_g1, 256, 0, stream>>>(x, rs, esorted, perm,
                                          wr1, wl1, b1, h1, N);
    k_g2f      <<<g_g2, 256, 0, stream>>>(h1, rs, esorted, perm,
                                          wr2, wl2, b2,
                                          f1w, f1b, f2w, f2b, out, N);
}

// Round 9
// 235.399 us; speedup vs baseline: 3.3992x; 3.3992x over previous
//
#include <hip/hip_runtime.h>

// Static float4 component access (folds to .x/.y/.z/.w after unroll).
#define F4E(v,i) ((i)==0?(v).x:((i)==1?(v).y:((i)==2?(v).z:(v).w)))

#define CHUNK 4096      // edges per partition block (512 threads x 8)
#define ITERS 8

__device__ inline float4 shfl4b(float4 v, int src) {
    float4 r;
    r.x = __shfl(v.x, src, 4); r.y = __shfl(v.y, src, 4);
    r.z = __shfl(v.z, src, 4); r.w = __shfl(v.w, src, 4);
    return r;
}
__device__ inline float4 shfl8b(float4 v, int src) {
    float4 r;
    r.x = __shfl(v.x, src, 8); r.y = __shfl(v.y, src, 8);
    r.z = __shfl(v.z, src, 8); r.w = __shfl(v.w, src, 8);
    return r;
}

// ---------------------------------------------------------------------------
// Bucket histogram: bucket = dst >> 8 (256 nodes per bucket), NB <= 512.
__global__ __launch_bounds__(512) void k_bhist(
    const int* __restrict__ ei, int* __restrict__ bhist, int E, int NB)
{
    __shared__ int cnt[512];
    int t = threadIdx.x;
    cnt[t] = 0;
    __syncthreads();
    int base = blockIdx.x * CHUNK;
#pragma unroll
    for (int i = 0; i < ITERS; ++i) {
        int e = base + i * 512 + t;
        if (e < E) {
            int dst = ei[E + e];
            atomicAdd(&cnt[dst >> 8], 1);
        }
    }
    __syncthreads();
    if (t < NB && cnt[t]) atomicAdd(&bhist[t], cnt[t]);
}

// Exclusive scan of bucket counts (NB <= 512), writes bstart + cursor init.
__global__ __launch_bounds__(512) void k_bscan(
    const int* __restrict__ bhist, int* __restrict__ bstart,
    int* __restrict__ gcursor, int NB, int E)
{
    __shared__ int s[512];
    int t = threadIdx.x;
    int v0 = (t < NB) ? bhist[t] : 0;
    s[t] = v0;
    __syncthreads();
    for (int off = 1; off < 512; off <<= 1) {
        int v = (t >= off) ? s[t - off] : 0;
        __syncthreads();
        s[t] += v;
        __syncthreads();
    }
    if (t < NB) { int ex = s[t] - v0; bstart[t] = ex; gcursor[t] = ex; }
    if (t == 0) bstart[NB] = E;
}

// Partition edges into bucket-contiguous packed list, coalesced flush.
// packed = (src << 8) | (dst & 255); requires N < 2^17 (holds: 100000).
__global__ __launch_bounds__(512) void k_partition(
    const int* __restrict__ ei, int* __restrict__ gcursor,
    int* __restrict__ epack, int E)
{
    __shared__ int cnt[512], sc[512], lbase[512], gbase[512], lcnt[512];
    __shared__ int stage[CHUNK];
    __shared__ unsigned short stageb[CHUNK];
    int t = threadIdx.x;
    cnt[t] = 0; lcnt[t] = 0;
    __syncthreads();

    int base = blockIdx.x * CHUNK;
    int pk[ITERS], bb[ITERS];
#pragma unroll
    for (int i = 0; i < ITERS; ++i) {
        int e = base + i * 512 + t;
        if (e < E) {
            int src = ei[e], dst = ei[E + e];
            pk[i] = (src << 8) | (dst & 255);
            bb[i] = dst >> 8;
            atomicAdd(&cnt[bb[i]], 1);
        } else bb[i] = -1;
    }
    __syncthreads();

    int v0 = cnt[t];
    sc[t] = v0;
    __syncthreads();
    for (int off = 1; off < 512; off <<= 1) {
        int v = (t >= off) ? sc[t - off] : 0;
        __syncthreads();
        sc[t] += v;
        __syncthreads();
    }
    lbase[t] = sc[t] - v0;
    if (v0 > 0) gbase[t] = atomicAdd(&gcursor[t], v0);
    __syncthreads();

#pragma unroll
    for (int i = 0; i < ITERS; ++i) {
        if (bb[i] >= 0) {
            int loc = atomicAdd(&lcnt[bb[i]], 1);
            int slot = lbase[bb[i]] + loc;
            stage[slot] = pk[i];
            stageb[slot] = (unsigned short)bb[i];
        }
    }
    __syncthreads();

    int m = min(CHUNK, E - base);
#pragma unroll
    for (int i = 0; i < ITERS; ++i) {
        int slot = i * 512 + t;
        if (slot < m) {
            int b = stageb[slot];
            epack[gbase[b] + (slot - lbase[b])] = stage[slot];
        }
    }
}

// ---------------------------------------------------------------------------
// Per-bucket counting sort by dst&255 -> per-node CSR (rs + esorted of src).
// Degree histogram accumulated in LDS first, one global add per (block,bin)
// (round-8 regression: per-thread global atomics to 64 bins serialized).
__global__ __launch_bounds__(256) void k_sort(
    const int* __restrict__ bstart, const int* __restrict__ epack,
    int* __restrict__ rs, int* __restrict__ esorted,
    int* __restrict__ dcnt, int N, int E)
{
    __shared__ int hist[256], cur[256], sc[256], dh[64];
    int t = threadIdx.x;
    int b = blockIdx.x;
    int s0 = bstart[b], s1 = bstart[b + 1];
    hist[t] = 0;
    if (t < 64) dh[t] = 0;
    __syncthreads();
    for (int e = s0 + t; e < s1; e += 256)
        atomicAdd(&hist[epack[e] & 255], 1);
    __syncthreads();

    int v0 = hist[t];
    sc[t] = v0;
    __syncthreads();
    for (int off = 1; off < 256; off <<= 1) {
        int v = (t >= off) ? sc[t - off] : 0;
        __syncthreads();
        sc[t] += v;
        __syncthreads();
    }
    int excl = sc[t] - v0;
    cur[t] = excl;
    int node = (b << 8) + t;
    if (node < N) {
        rs[node] = s0 + excl;
        atomicAdd(&dh[min(v0, 63)], 1);      // LDS histogram (native ds_add)
    }
    if (b == 0 && t == 0) rs[N] = E;
    __syncthreads();
    if (t < 64 && dh[t]) atomicAdd(&dcnt[t], dh[t]);   // 64 adds per block

    for (int e = s0 + t; e < s1; e += 256) {
        int pk = epack[e];
        int dlo = pk & 255;
        int pos = s0 + atomicAdd(&cur[dlo], 1);
        esorted[pos] = ((unsigned)pk) >> 8;
    }
}

// ---------------------------------------------------------------------------
// Degree-binned node permutation, block-aggregated cursors:
// per-block LDS 64-bin histogram -> one global reserve per (block,bin) ->
// local scatter. (Round-8 regression: per-thread global dcur atomics.)
__global__ __launch_bounds__(256) void k_perm(
    const int* __restrict__ rs, const int* __restrict__ dcnt,
    int* __restrict__ dcur, int* __restrict__ perm, int N)
{
    __shared__ int sstart[64], bcnt[64], gb[64], lcnt[64];
    int t = threadIdx.x;
    if (t < 64) { bcnt[t] = 0; lcnt[t] = 0; }
    __syncthreads();

    int node = blockIdx.x * 256 + t;
    int bin = -1;
    if (node < N) {
        int deg = rs[node + 1] - rs[node];
        bin = min(deg, 63);
        atomicAdd(&bcnt[bin], 1);
    }
    __syncthreads();

    if (t < 64) {                        // one wave: shfl-scan global bins
        int v = dcnt[t];
        int incl = v;
#pragma unroll
        for (int d = 1; d < 64; d <<= 1) {
            int o = __shfl_up(incl, d, 64);
            if (t >= d) incl += o;
        }
        sstart[t] = incl - v;
        if (bcnt[t]) gb[t] = atomicAdd(&dcur[t], bcnt[t]);
    }
    __syncthreads();

    if (node < N) {
        int loc = atomicAdd(&lcnt[bin], 1);
        perm[sstart[bin] + gb[bin] + loc] = node;
    }
}

// ---------------------------------------------------------------------------
// Fused gather(F=16) + layer1: 4 threads per node, degree-binned order.
__global__ __launch_bounds__(256) void k_g1f(
    const float* __restrict__ x, const int* __restrict__ rs,
    const int* __restrict__ esrc, const int* __restrict__ perm,
    const float* __restrict__ wroot, const float* __restrict__ wrel,
    const float* __restrict__ bias, float* __restrict__ h1, int N)
{
    __shared__ float4 s_wr[128], s_wl[128], s_b[8];   // 16x32 each, bias 32
    int t = threadIdx.x;
    if (t < 128) {
        s_wr[t] = reinterpret_cast<const float4*>(wroot)[t];
        s_wl[t] = reinterpret_cast<const float4*>(wrel)[t];
    }
    if (t < 8) s_b[t] = reinterpret_cast<const float4*>(bias)[t];
    __syncthreads();

    int tid = blockIdx.x * 256 + t;
    int q = tid >> 2, p = tid & 3;
    if (q >= N) return;
    int n = perm[q];
    int s0 = rs[n], s1 = rs[n + 1];
    float4 g = make_float4(0.f, 0.f, 0.f, 0.f);
    int e = s0;
    for (; e + 3 < s1; e += 4) {
        int sa = esrc[e], sb = esrc[e + 1], sc = esrc[e + 2], sd = esrc[e + 3];
        float4 v0 = *reinterpret_cast<const float4*>(x + (size_t)sa * 16 + p * 4);
        float4 v1 = *reinterpret_cast<const float4*>(x + (size_t)sb * 16 + p * 4);
        float4 v2 = *reinterpret_cast<const float4*>(x + (size_t)sc * 16 + p * 4);
        float4 v3 = *reinterpret_cast<const float4*>(x + (size_t)sd * 16 + p * 4);
        g.x += (v0.x + v1.x) + (v2.x + v3.x);
        g.y += (v0.y + v1.y) + (v2.y + v3.y);
        g.z += (v0.z + v1.z) + (v2.z + v3.z);
        g.w += (v0.w + v1.w) + (v2.w + v3.w);
    }
    for (; e < s1; ++e) {
        int sa = esrc[e];
        float4 v0 = *reinterpret_cast<const float4*>(x + (size_t)sa * 16 + p * 4);
        g.x += v0.x; g.y += v0.y; g.z += v0.z; g.w += v0.w;
    }
    float4 a = *reinterpret_cast<const float4*>(x + (size_t)n * 16 + p * 4);

    int jb = p * 2;                          // my 2 float4 columns of 8
    float4 acc0 = s_b[jb], acc1 = s_b[jb + 1];
#pragma unroll
    for (int kc = 0; kc < 4; ++kc) {
        float4 a4 = shfl4b(a, kc);
        float4 g4 = shfl4b(g, kc);
#pragma unroll
        for (int kk = 0; kk < 4; ++kk) {
            float av = F4E(a4, kk), gv = F4E(g4, kk);
            int k = kc * 4 + kk;
            float4 wr0 = s_wr[k * 8 + jb], wr1 = s_wr[k * 8 + jb + 1];
            float4 wl0 = s_wl[k * 8 + jb], wl1 = s_wl[k * 8 + jb + 1];
            acc0.x += av * wr0.x + gv * wl0.x;
            acc0.y += av * wr0.y + gv * wl0.y;
            acc0.z += av * wr0.z + gv * wl0.z;
            acc0.w += av * wr0.w + gv * wl0.w;
            acc1.x += av * wr1.x + gv * wl1.x;
            acc1.y += av * wr1.y + gv * wl1.y;
            acc1.z += av * wr1.z + gv * wl1.z;
            acc1.w += av * wr1.w + gv * wl1.w;
        }
    }
    acc0.x = fmaxf(acc0.x, 0.f); acc0.y = fmaxf(acc0.y, 0.f);
    acc0.z = fmaxf(acc0.z, 0.f); acc0.w = fmaxf(acc0.w, 0.f);
    acc1.x = fmaxf(acc1.x, 0.f); acc1.y = fmaxf(acc1.y, 0.f);
    acc1.w = fmaxf(acc1.w, 0.f); acc1.z = fmaxf(acc1.z, 0.f);
    float4* o = reinterpret_cast<float4*>(h1 + (size_t)n * 32 + p * 8);
    o[0] = acc0; o[1] = acc1;
}

// ---------------------------------------------------------------------------
// Fused gather(F=32) + layer2 + fc1 + fc2: 8 threads per node,
// degree-binned order. Writes final output directly.
__global__ __launch_bounds__(256) void k_g2f(
    const float* __restrict__ h1, const int* __restrict__ rs,
    const int* __restrict__ esrc, const int* __restrict__ perm,
    const float* __restrict__ wroot, const float* __restrict__ wrel,
    const float* __restrict__ bias,
    const float* __restrict__ f1w, const float* __restrict__ f1b,
    const float* __restrict__ f2w, const float* __restrict__ f2b,
    float* __restrict__ out, int N)
{
    __shared__ float4 s_wr[512], s_wl[512], s_b[16];  // 32x64 weights, bias 64
    __shared__ float4 s_f1[512];                      // 64x32, jc-swizzled
    __shared__ float  s_f2[512];                      // 32x16
    __shared__ float4 s_b1[8];
    __shared__ float  s_b2[16];
    int t = threadIdx.x;
    for (int i = t; i < 512; i += 256) {
        s_wr[i] = reinterpret_cast<const float4*>(wroot)[i];
        s_wl[i] = reinterpret_cast<const float4*>(wrel)[i];
        // swizzle: row k (= i>>3), col jc (= i&7) stored at jc' = (jc + (k>>3)) & 7
        // so the 8 k-split lanes (k = p*8+kk, k>>3 == p) hit 8 distinct banks.
        int k = i >> 3, jc = i & 7;
        s_f1[(i & ~7) | ((jc + (k >> 3)) & 7)] = reinterpret_cast<const float4*>(f1w)[i];
        s_f2[i] = f2w[i];
    }
    if (t < 16) s_b[t]  = reinterpret_cast<const float4*>(bias)[t];
    if (t < 8)  s_b1[t] = reinterpret_cast<const float4*>(f1b)[t];
    if (t < 16) s_b2[t] = f2b[t];
    __syncthreads();

    int tid = blockIdx.x * 256 + t;
    int q = tid >> 3, p = tid & 7;
    if (q >= N) return;
    int n = perm[q];

    // gather my float4 slice of agg2 (4 loads in flight)
    int s0 = rs[n], s1 = rs[n + 1];
    float4 g = make_float4(0.f, 0.f, 0.f, 0.f);
    int e = s0;
    for (; e + 3 < s1; e += 4) {
        int sa = esrc[e], sb = esrc[e + 1], sc = esrc[e + 2], sd = esrc[e + 3];
        float4 v0 = *reinterpret_cast<const float4*>(h1 + (size_t)sa * 32 + p * 4);
        float4 v1 = *reinterpret_cast<const float4*>(h1 + (size_t)sb * 32 + p * 4);
        float4 v2 = *reinterpret_cast<const float4*>(h1 + (size_t)sc * 32 + p * 4);
        float4 v3 = *reinterpret_cast<const float4*>(h1 + (size_t)sd * 32 + p * 4);
        g.x += (v0.x + v1.x) + (v2.x + v3.x);
        g.y += (v0.y + v1.y) + (v2.y + v3.y);
        g.z += (v0.z + v1.z) + (v2.z + v3.z);
        g.w += (v0.w + v1.w) + (v2.w + v3.w);
    }
    for (; e < s1; ++e) {
        int sa = esrc[e];
        float4 v0 = *reinterpret_cast<const float4*>(h1 + (size_t)sa * 32 + p * 4);
        g.x += v0.x; g.y += v0.y; g.z += v0.z; g.w += v0.w;
    }
    float4 a = *reinterpret_cast<const float4*>(h1 + (size_t)n * 32 + p * 4);

    // layer2: my 8 of 64 h2 outputs (j in [p*8, p*8+8)), jb = p*2 float4 cols
    int jb = p * 2;
    float4 acc0 = s_b[jb], acc1 = s_b[jb + 1];
#pragma unroll
    for (int kc = 0; kc < 8; ++kc) {
        float4 a4 = shfl8b(a, kc);
        float4 g4 = shfl8b(g, kc);
#pragma unroll
        for (int kk = 0; kk < 4; ++kk) {
            float av = F4E(a4, kk), gv = F4E(g4, kk);
            int k = kc * 4 + kk;
            float4 wr0 = s_wr[k * 16 + jb], wr1 = s_wr[k * 16 + jb + 1];
            float4 wl0 = s_wl[k * 16 + jb], wl1 = s_wl[k * 16 + jb + 1];
            acc0.x += av * wr0.x + gv * wl0.x;
            acc0.y += av * wr0.y + gv * wl0.y;
            acc0.z += av * wr0.z + gv * wl0.z;
            acc0.w += av * wr0.w + gv * wl0.w;
            acc1.x += av * wr1.x + gv * wl1.x;
            acc1.y += av * wr1.y + gv * wl1.y;
            acc1.z += av * wr1.z + gv * wl1.z;
            acc1.w += av * wr1.w + gv * wl1.w;
        }
    }
    acc0.x = fmaxf(acc0.x, 0.f); acc0.y = fmaxf(acc0.y, 0.f);
    acc0.z = fmaxf(acc0.z, 0.f); acc0.w = fmaxf(acc0.w, 0.f);
    acc1.x = fmaxf(acc1.x, 0.f); acc1.y = fmaxf(acc1.y, 0.f);
    acc1.z = fmaxf(acc1.z, 0.f); acc1.w = fmaxf(acc1.w, 0.f);

    // fc1 k-split: my 8 h2 values are k = p*8 + kk; partials over all 32 outs.
    // Read at swizzled slot ((jc+p)&7) -> retrieves ORIGINAL column jc;
    // accumulate into f[jc] (compile-time index) for the butterfly reduce.
    float4 f[8];
    float4 z4 = make_float4(0.f, 0.f, 0.f, 0.f);
#pragma unroll
    for (int jc = 0; jc < 8; ++jc) f[jc] = p ? z4 : s_b1[jc];
#pragma unroll
    for (int kk = 0; kk < 8; ++kk) {
        float hv = (kk < 4) ? F4E(acc0, kk) : F4E(acc1, kk - 4);
        int k = p * 8 + kk;
        int row = k * 8;
#pragma unroll
        for (int jc = 0; jc < 8; ++jc) {
            float4 w = s_f1[row | ((jc + p) & 7)];
            f[jc].x += hv * w.x; f[jc].y += hv * w.y;
            f[jc].z += hv * w.z; f[jc].w += hv * w.w;
        }
    }
    // butterfly reduce across the 8-lane group + relu
#pragma unroll
    for (int m = 1; m < 8; m <<= 1) {
#pragma unroll
        for (int jc = 0; jc < 8; ++jc) {
            f[jc].x += __shfl_xor(f[jc].x, m);
            f[jc].y += __shfl_xor(f[jc].y, m);
            f[jc].z += __shfl_xor(f[jc].z, m);
            f[jc].w += __shfl_xor(f[jc].w, m);
        }
    }
#pragma unroll
    for (int jc = 0; jc < 8; ++jc) {
        f[jc].x = fmaxf(f[jc].x, 0.f); f[jc].y = fmaxf(f[jc].y, 0.f);
        f[jc].z = fmaxf(f[jc].z, 0.f); f[jc].w = fmaxf(f[jc].w, 0.f);
    }

    // fc2 j-split: my 2 of 16 outputs (j = p*2, p*2+1).
    float o0 = s_b2[p * 2], o1 = s_b2[p * 2 + 1];
#pragma unroll
    for (int k2 = 0; k2 < 32; ++k2) {
        float av = F4E(f[k2 >> 2], k2 & 3);
        o0 += av * s_f2[k2 * 16 + p * 2];
        o1 += av * s_f2[k2 * 16 + p * 2 + 1];
    }
    float2* o = reinterpret_cast<float2*>(out + (size_t)n * 16 + p * 2);
    *o = make_float2(o0, o1);
}

// ---------------------------------------------------------------------------
extern "C" void kernel_launch(void* const* d_in, const int* in_sizes, int n_in,
                              void* d_out, int out_size, void* d_ws, size_t ws_size,
                              hipStream_t stream)
{
    const float* x   = (const float*)d_in[0];
    const int*   ei  = (const int*)d_in[1];
    const float* wr1 = (const float*)d_in[2];
    const float* wl1 = (const float*)d_in[3];
    const float* b1  = (const float*)d_in[4];
    const float* wr2 = (const float*)d_in[5];
    const float* wl2 = (const float*)d_in[6];
    const float* b2  = (const float*)d_in[7];
    const float* f1w = (const float*)d_in[8];
    const float* f1b = (const float*)d_in[9];
    const float* f2w = (const float*)d_in[10];
    const float* f2b = (const float*)d_in[11];
    float* out = (float*)d_out;

    const int N  = in_sizes[0] / 16;
    const int E  = in_sizes[1] / 2;
    const int NB = (N + 255) >> 8;      // 256 nodes per bucket, NB <= 512

    // Workspace layout (floats/ints, no aliasing; ~26.8MB of >=51.2MB):
    //   h1      : N*32 floats   12.8 MB
    //   esorted : E ints         6.4 MB
    //   epack   : E ints         6.4 MB
    //   rs      : N+1 ints
    //   [bhist NB | dcnt 64 | dcur 64]  <- single zeroing memset
    //   bstart  : NB+1 ints, gcursor : NB ints
    //   perm    : N ints
    float* ws      = (float*)d_ws;
    float* h1      = ws;
    int*   esorted = (int*)(ws + (size_t)N * 32);
    int*   epack   = esorted + E;
    int*   rs      = epack + E;
    int*   bhist   = rs + N + 1;
    int*   dcnt    = bhist + NB;
    int*   dcur    = dcnt + 64;
    int*   bstart  = dcur + 64;
    int*   gcursor = bstart + NB + 1;
    int*   perm    = gcursor + NB;

    hipMemsetAsync(bhist, 0, (size_t)(NB + 128) * sizeof(int), stream);

    int nchunk = (E + CHUNK - 1) / CHUNK;
    int g_n  = (N + 255) / 256;
    int g_g1 = (N * 4 + 255) / 256;
    int g_g2 = (N * 8 + 255) / 256;

    k_bhist    <<<nchunk, 512, 0, stream>>>(ei, bhist, E, NB);
    k_bscan    <<<1,      512, 0, stream>>>(bhist, bstart, gcursor, NB, E);
    k_partition<<<nchunk, 512, 0, stream>>>(ei, gcursor, epack, E);
    k_sort     <<<NB,     256, 0, stream>>>(bstart, epack, rs, esorted, dcnt, N, E);
    k_perm     <<<g_n,    256, 0, stream>>>(rs, dcnt, dcur, perm, N);

    k_g1f      <<<g_g1, 256, 0, stream>>>(x, rs, esorted, perm,
                                          wr1, wl1, b1, h1, N);
    k_g2f      <<<g_g2, 256, 0, stream>>>(h1, rs, esorted, perm,
                                          wr2, wl2, b2,
                                          f1w, f1b, f2w, f2b, out, N);
}

// Round 11
// 220.574 us; speedup vs baseline: 3.6276x; 1.0672x over previous
//
#include <hip/hip_runtime.h>

// Static float4 component access (folds to .x/.y/.z/.w after unroll).
#define F4E(v,i) ((i)==0?(v).x:((i)==1?(v).y:((i)==2?(v).z:(v).w)))

#define CHUNK 4096      // edges per partition block (512 threads x 8)
#define ITERS 8

__device__ inline float4 shfl4b(float4 v, int src) {
    float4 r;
    r.x = __shfl(v.x, src, 4); r.y = __shfl(v.y, src, 4);
    r.z = __shfl(v.z, src, 4); r.w = __shfl(v.w, src, 4);
    return r;
}
__device__ inline float4 shfl8b(float4 v, int src) {
    float4 r;
    r.x = __shfl(v.x, src, 8); r.y = __shfl(v.y, src, 8);
    r.z = __shfl(v.z, src, 8); r.w = __shfl(v.w, src, 8);
    return r;
}

// fp32 -> bf16 (RNE) pack of two values into one uint (lo = a, hi = b).
__device__ inline unsigned packbf2(float a, float b) {
    unsigned ua = __float_as_uint(a), ub = __float_as_uint(b);
    ua = (ua + 0x7fffu + ((ua >> 16) & 1u)) >> 16;
    ub = (ub + 0x7fffu + ((ub >> 16) & 1u)) >> 16;
    return ua | (ub << 16);
}
// bf16 pair (one uint) -> two floats.
__device__ inline float bflo(unsigned w) { return __uint_as_float(w << 16); }
__device__ inline float bfhi(unsigned w) { return __uint_as_float(w & 0xffff0000u); }

// ---------------------------------------------------------------------------
// Bucket histogram: bucket = dst >> 8 (256 nodes per bucket), NB <= 512.
__global__ __launch_bounds__(512) void k_bhist(
    const int* __restrict__ ei, int* __restrict__ bhist, int E, int NB)
{
    __shared__ int cnt[512];
    int t = threadIdx.x;
    cnt[t] = 0;
    __syncthreads();
    int base = blockIdx.x * CHUNK;
#pragma unroll
    for (int i = 0; i < ITERS; ++i) {
        int e = base + i * 512 + t;
        if (e < E) {
            int dst = ei[E + e];
            atomicAdd(&cnt[dst >> 8], 1);
        }
    }
    __syncthreads();
    if (t < NB && cnt[t]) atomicAdd(&bhist[t], cnt[t]);
}

// Exclusive scan of bucket counts (NB <= 512), writes bstart + cursor init.
__global__ __launch_bounds__(512) void k_bscan(
    const int* __restrict__ bhist, int* __restrict__ bstart,
    int* __restrict__ gcursor, int NB, int E)
{
    __shared__ int s[512];
    int t = threadIdx.x;
    int v0 = (t < NB) ? bhist[t] : 0;
    s[t] = v0;
    __syncthreads();
    for (int off = 1; off < 512; off <<= 1) {
        int v = (t >= off) ? s[t - off] : 0;
        __syncthreads();
        s[t] += v;
        __syncthreads();
    }
    if (t < NB) { int ex = s[t] - v0; bstart[t] = ex; gcursor[t] = ex; }
    if (t == 0) bstart[NB] = E;
}

// Partition edges into bucket-contiguous packed list, coalesced flush.
// packed = (src << 8) | (dst & 255); requires N < 2^17 (holds: 100000).
__global__ __launch_bounds__(512) void k_partition(
    const int* __restrict__ ei, int* __restrict__ gcursor,
    int* __restrict__ epack, int E)
{
    __shared__ int cnt[512], sc[512], lbase[512], gbase[512], lcnt[512];
    __shared__ int stage[CHUNK];
    __shared__ unsigned short stageb[CHUNK];
    int t = threadIdx.x;
    cnt[t] = 0; lcnt[t] = 0;
    __syncthreads();

    int base = blockIdx.x * CHUNK;
    int pk[ITERS], bb[ITERS];
#pragma unroll
    for (int i = 0; i < ITERS; ++i) {
        int e = base + i * 512 + t;
        if (e < E) {
            int src = ei[e], dst = ei[E + e];
            pk[i] = (src << 8) | (dst & 255);
            bb[i] = dst >> 8;
            atomicAdd(&cnt[bb[i]], 1);
        } else bb[i] = -1;
    }
    __syncthreads();

    int v0 = cnt[t];
    sc[t] = v0;
    __syncthreads();
    for (int off = 1; off < 512; off <<= 1) {
        int v = (t >= off) ? sc[t - off] : 0;
        __syncthreads();
        sc[t] += v;
        __syncthreads();
    }
    lbase[t] = sc[t] - v0;
    if (v0 > 0) gbase[t] = atomicAdd(&gcursor[t], v0);
    __syncthreads();

#pragma unroll
    for (int i = 0; i < ITERS; ++i) {
        if (bb[i] >= 0) {
            int loc = atomicAdd(&lcnt[bb[i]], 1);
            int slot = lbase[bb[i]] + loc;
            stage[slot] = pk[i];
            stageb[slot] = (unsigned short)bb[i];
        }
    }
    __syncthreads();

    int m = min(CHUNK, E - base);
#pragma unroll
    for (int i = 0; i < ITERS; ++i) {
        int slot = i * 512 + t;
        if (slot < m) {
            int b = stageb[slot];
            epack[gbase[b] + (slot - lbase[b])] = stage[slot];
        }
    }
}

// ---------------------------------------------------------------------------
// Per-bucket counting sort by dst&255 -> per-node CSR (rs + esorted of src).
__global__ __launch_bounds__(256) void k_sort(
    const int* __restrict__ bstart, const int* __restrict__ epack,
    int* __restrict__ rs, int* __restrict__ esorted, int N, int E)
{
    __shared__ int hist[256], cur[256], sc[256];
    int t = threadIdx.x;
    int b = blockIdx.x;
    int s0 = bstart[b], s1 = bstart[b + 1];
    hist[t] = 0;
    __syncthreads();
    for (int e = s0 + t; e < s1; e += 256)
        atomicAdd(&hist[epack[e] & 255], 1);
    __syncthreads();

    int v0 = hist[t];
    sc[t] = v0;
    __syncthreads();
    for (int off = 1; off < 256; off <<= 1) {
        int v = (t >= off) ? sc[t - off] : 0;
        __syncthreads();
        sc[t] += v;
        __syncthreads();
    }
    int excl = sc[t] - v0;
    cur[t] = excl;
    int node = (b << 8) + t;
    if (node < N) rs[node] = s0 + excl;
    if (b == 0 && t == 0) rs[N] = E;
    __syncthreads();

    for (int e = s0 + t; e < s1; e += 256) {
        int pk = epack[e];
        int dlo = pk & 255;
        int pos = s0 + atomicAdd(&cur[dlo], 1);
        esorted[pos] = ((unsigned)pk) >> 8;
    }
}

// ---------------------------------------------------------------------------
// Fused gather(F=16) + layer1: 4 threads per node.
// Writes h1 as bf16 (RNE) -- halves layer-2 gather traffic.
__global__ __launch_bounds__(256) void k_g1f(
    const float* __restrict__ x, const int* __restrict__ rs,
    const int* __restrict__ esrc,
    const float* __restrict__ wroot, const float* __restrict__ wrel,
    const float* __restrict__ bias, unsigned short* __restrict__ h1, int N)
{
    __shared__ float4 s_wr[128], s_wl[128], s_b[8];   // 16x32 each, bias 32
    int t = threadIdx.x;
    if (t < 128) {
        s_wr[t] = reinterpret_cast<const float4*>(wroot)[t];
        s_wl[t] = reinterpret_cast<const float4*>(wrel)[t];
    }
    if (t < 8) s_b[t] = reinterpret_cast<const float4*>(bias)[t];
    __syncthreads();

    int tid = blockIdx.x * 256 + t;
    int n = tid >> 2, p = tid & 3;
    if (n >= N) return;
    int s0 = rs[n], s1 = rs[n + 1];
    float4 g = make_float4(0.f, 0.f, 0.f, 0.f);
    int e = s0;
    for (; e + 7 < s1; e += 8) {                   // 8 loads in flight
        float4 v[8];
#pragma unroll
        for (int u = 0; u < 8; ++u) {
            int src = esrc[e + u];
            v[u] = *reinterpret_cast<const float4*>(x + (size_t)src * 16 + p * 4);
        }
#pragma unroll
        for (int u = 0; u < 8; ++u) {
            g.x += v[u].x; g.y += v[u].y; g.z += v[u].z; g.w += v[u].w;
        }
    }
    for (; e < s1; ++e) {
        int src = esrc[e];
        float4 v0 = *reinterpret_cast<const float4*>(x + (size_t)src * 16 + p * 4);
        g.x += v0.x; g.y += v0.y; g.z += v0.z; g.w += v0.w;
    }
    float4 a = *reinterpret_cast<const float4*>(x + (size_t)n * 16 + p * 4);

    int jb = p * 2;                          // my 2 float4 columns of 8
    float4 acc0 = s_b[jb], acc1 = s_b[jb + 1];
#pragma unroll
    for (int kc = 0; kc < 4; ++kc) {
        float4 a4 = shfl4b(a, kc);
        float4 g4 = shfl4b(g, kc);
#pragma unroll
        for (int kk = 0; kk < 4; ++kk) {
            float av = F4E(a4, kk), gv = F4E(g4, kk);
            int k = kc * 4 + kk;
            float4 wr0 = s_wr[k * 8 + jb], wr1 = s_wr[k * 8 + jb + 1];
            float4 wl0 = s_wl[k * 8 + jb], wl1 = s_wl[k * 8 + jb + 1];
            acc0.x += av * wr0.x + gv * wl0.x;
            acc0.y += av * wr0.y + gv * wl0.y;
            acc0.z += av * wr0.z + gv * wl0.z;
            acc0.w += av * wr0.w + gv * wl0.w;
            acc1.x += av * wr1.x + gv * wl1.x;
            acc1.y += av * wr1.y + gv * wl1.y;
            acc1.z += av * wr1.z + gv * wl1.z;
            acc1.w += av * wr1.w + gv * wl1.w;
        }
    }
    acc0.x = fmaxf(acc0.x, 0.f); acc0.y = fmaxf(acc0.y, 0.f);
    acc0.z = fmaxf(acc0.z, 0.f); acc0.w = fmaxf(acc0.w, 0.f);
    acc1.x = fmaxf(acc1.x, 0.f); acc1.y = fmaxf(acc1.y, 0.f);
    acc1.z = fmaxf(acc1.z, 0.f); acc1.w = fmaxf(acc1.w, 0.f);

    // pack 8 outputs (j = p*8 .. p*8+8) as bf16 into one 16B store
    uint4 w;
    w.x = packbf2(acc0.x, acc0.y);
    w.y = packbf2(acc0.z, acc0.w);
    w.z = packbf2(acc1.x, acc1.y);
    w.w = packbf2(acc1.z, acc1.w);
    reinterpret_cast<uint4*>(h1 + (size_t)n * 32)[p] = w;
}

// ---------------------------------------------------------------------------
// Fused gather(F=32, bf16 rows) + layer2 + fc1 + fc2: 8 threads per node.
__global__ __launch_bounds__(256) void k_g2f(
    const unsigned short* __restrict__ h1, const int* __restrict__ rs,
    const int* __restrict__ esrc,
    const float* __restrict__ wroot, const float* __restrict__ wrel,
    const float* __restrict__ bias,
    const float* __restrict__ f1w, const float* __restrict__ f1b,
    const float* __restrict__ f2w, const float* __restrict__ f2b,
    float* __restrict__ out, int N)
{
    __shared__ float4 s_wr[512], s_wl[512], s_b[16];  // 32x64 weights, bias 64
    __shared__ float4 s_f1[512];                      // 64x32, jc-swizzled
    __shared__ float  s_f2[512];                      // 32x16
    __shared__ float4 s_b1[8];
    __shared__ float  s_b2[16];
    int t = threadIdx.x;
    for (int i = t; i < 512; i += 256) {
        s_wr[i] = reinterpret_cast<const float4*>(wroot)[i];
        s_wl[i] = reinterpret_cast<const float4*>(wrel)[i];
        // swizzle: row k (= i>>3), col jc (= i&7) stored at jc' = (jc + (k>>3)) & 7
        int k = i >> 3, jc = i & 7;
        s_f1[(i & ~7) | ((jc + (k >> 3)) & 7)] = reinterpret_cast<const float4*>(f1w)[i];
        s_f2[i] = f2w[i];
    }
    if (t < 16) s_b[t]  = reinterpret_cast<const float4*>(bias)[t];
    if (t < 8)  s_b1[t] = reinterpret_cast<const float4*>(f1b)[t];
    if (t < 16) s_b2[t] = f2b[t];
    __syncthreads();

    int tid = blockIdx.x * 256 + t;
    int n = tid >> 3, p = tid & 7;
    if (n >= N) return;

    // gather my 4-feature slice of agg2 from bf16 h1 rows (8B/lane/edge,
    // 8 loads in flight)
    int s0 = rs[n], s1 = rs[n + 1];
    float4 g = make_float4(0.f, 0.f, 0.f, 0.f);
    int e = s0;
    for (; e + 7 < s1; e += 8) {
        uint2 w[8];
#pragma unroll
        for (int u = 0; u < 8; ++u) {
            int src = esrc[e + u];
            w[u] = reinterpret_cast<const uint2*>(h1 + (size_t)src * 32)[p];
        }
#pragma unroll
        for (int u = 0; u < 8; ++u) {
            g.x += bflo(w[u].x); g.y += bfhi(w[u].x);
            g.z += bflo(w[u].y); g.w += bfhi(w[u].y);
        }
    }
    for (; e < s1; ++e) {
        int src = esrc[e];
        uint2 w0 = reinterpret_cast<const uint2*>(h1 + (size_t)src * 32)[p];
        g.x += bflo(w0.x); g.y += bfhi(w0.x);
        g.z += bflo(w0.y); g.w += bfhi(w0.y);
    }
    uint2 aw = reinterpret_cast<const uint2*>(h1 + (size_t)n * 32)[p];
    float4 a = make_float4(bflo(aw.x), bfhi(aw.x), bflo(aw.y), bfhi(aw.y));

    // layer2: my 8 of 64 h2 outputs (j in [p*8, p*8+8)), jb = p*2 float4 cols
    int jb = p * 2;
    float4 acc0 = s_b[jb], acc1 = s_b[jb + 1];
#pragma unroll
    for (int kc = 0; kc < 8; ++kc) {
        float4 a4 = shfl8b(a, kc);
        float4 g4 = shfl8b(g, kc);
#pragma unroll
        for (int kk = 0; kk < 4; ++kk) {
            float av = F4E(a4, kk), gv = F4E(g4, kk);
            int k = kc * 4 + kk;
            float4 wr0 = s_wr[k * 16 + jb], wr1 = s_wr[k * 16 + jb + 1];
            float4 wl0 = s_wl[k * 16 + jb], wl1 = s_wl[k * 16 + jb + 1];
            acc0.x += av * wr0.x + gv * wl0.x;
            acc0.y += av * wr0.y + gv * wl0.y;
            acc0.z += av * wr0.z + gv * wl0.z;
            acc0.w += av * wr0.w + gv * wl0.w;
            acc1.x += av * wr1.x + gv * wl1.x;
            acc1.y += av * wr1.y + gv * wl1.y;
            acc1.z += av * wr1.z + gv * wl1.z;
            acc1.w += av * wr1.w + gv * wl1.w;
        }
    }
    acc0.x = fmaxf(acc0.x, 0.f); acc0.y = fmaxf(acc0.y, 0.f);
    acc0.z = fmaxf(acc0.z, 0.f); acc0.w = fmaxf(acc0.w, 0.f);
    acc1.x = fmaxf(acc1.x, 0.f); acc1.y = fmaxf(acc1.y, 0.f);
    acc1.z = fmaxf(acc1.z, 0.f); acc1.w = fmaxf(acc1.w, 0.f);

    // fc1 k-split: my 8 h2 values are k = p*8 + kk; partials over all 32 outs.
    float4 f[8];
    float4 z4 = make_float4(0.f, 0.f, 0.f, 0.f);
#pragma unroll
    for (int jc = 0; jc < 8; ++jc) f[jc] = p ? z4 : s_b1[jc];
#pragma unroll
    for (int kk = 0; kk < 8; ++kk) {
        float hv = (kk < 4) ? F4E(acc0, kk) : F4E(acc1, kk - 4);
        int k = p * 8 + kk;
        int row = k * 8;
#pragma unroll
        for (int jc = 0; jc < 8; ++jc) {
            float4 w = s_f1[row | ((jc + p) & 7)];
            f[jc].x += hv * w.x; f[jc].y += hv * w.y;
            f[jc].z += hv * w.z; f[jc].w += hv * w.w;
        }
    }
    // butterfly reduce across the 8-lane group + relu
#pragma unroll
    for (int m = 1; m < 8; m <<= 1) {
#pragma unroll
        for (int jc = 0; jc < 8; ++jc) {
            f[jc].x += __shfl_xor(f[jc].x, m);
            f[jc].y += __shfl_xor(f[jc].y, m);
            f[jc].z += __shfl_xor(f[jc].z, m);
            f[jc].w += __shfl_xor(f[jc].w, m);
        }
    }
#pragma unroll
    for (int jc = 0; jc < 8; ++jc) {
        f[jc].x = fmaxf(f[jc].x, 0.f); f[jc].y = fmaxf(f[jc].y, 0.f);
        f[jc].z = fmaxf(f[jc].z, 0.f); f[jc].w = fmaxf(f[jc].w, 0.f);
    }

    // fc2 j-split: my 2 of 16 outputs (j = p*2, p*2+1).
    float o0 = s_b2[p * 2], o1 = s_b2[p * 2 + 1];
#pragma unroll
    for (int k2 = 0; k2 < 32; ++k2) {
        float av = F4E(f[k2 >> 2], k2 & 3);
        o0 += av * s_f2[k2 * 16 + p * 2];
        o1 += av * s_f2[k2 * 16 + p * 2 + 1];
    }
    float2* o = reinterpret_cast<float2*>(out + (size_t)n * 16 + p * 2);
    *o = make_float2(o0, o1);
}

// ---------------------------------------------------------------------------
extern "C" void kernel_launch(void* const* d_in, const int* in_sizes, int n_in,
                              void* d_out, int out_size, void* d_ws, size_t ws_size,
                              hipStream_t stream)
{
    const float* x   = (const float*)d_in[0];
    const int*   ei  = (const int*)d_in[1];
    const float* wr1 = (const float*)d_in[2];
    const float* wl1 = (const float*)d_in[3];
    const float* b1  = (const float*)d_in[4];
    const float* wr2 = (const float*)d_in[5];
    const float* wl2 = (const float*)d_in[6];
    const float* b2  = (const float*)d_in[7];
    const float* f1w = (const float*)d_in[8];
    const float* f1b = (const float*)d_in[9];
    const float* f2w = (const float*)d_in[10];
    const float* f2b = (const float*)d_in[11];
    float* out = (float*)d_out;

    const int N  = in_sizes[0] / 16;
    const int E  = in_sizes[1] / 2;
    const int NB = (N + 255) >> 8;      // 256 nodes per bucket, NB <= 512

    // Workspace layout (no aliasing; ~20MB of >=51.2MB):
    //   h1      : N*32 bf16 (= N*16 float slots)   6.4 MB
    //   esorted : E ints
    //   epack   : E ints
    //   rs      : N+1 ints; bhist/bstart/gcursor tiny
    float*          ws      = (float*)d_ws;
    unsigned short* h1      = (unsigned short*)ws;
    int*            esorted = (int*)(ws + (size_t)N * 16);
    int*            epack   = esorted + E;
    int*            rs      = epack + E;
    int*            bhist   = rs + N + 1;
    int*            bstart  = bhist + NB;
    int*            gcursor = bstart + NB + 1;

    hipMemsetAsync(bhist, 0, (size_t)NB * sizeof(int), stream);

    int nchunk = (E + CHUNK - 1) / CHUNK;
    int g_g1 = (N * 4 + 255) / 256;
    int g_g2 = (N * 8 + 255) / 256;

    k_bhist    <<<nchunk, 512, 0, stream>>>(ei, bhist, E, NB);
    k_bscan    <<<1,      512, 0, stream>>>(bhist, bstart, gcursor, NB, E);
    k_partition<<<nchunk, 512, 0, stream>>>(ei, gcursor, epack, E);
    k_sort     <<<NB,     256, 0, stream>>>(bstart, epack, rs, esorted, N, E);

    k_g1f      <<<g_g1, 256, 0, stream>>>(x, rs, esorted, wr1, wl1, b1, h1, N);
    k_g2f      <<<g_g2, 256, 0, stream>>>(h1, rs, esorted, wr2, wl2, b2,
                                          f1w, f1b, f2w, f2b, out, N);
}

// Round 12
// 215.878 us; speedup vs baseline: 3.7066x; 1.0218x over previous
//
#include <hip/hip_runtime.h>

// Static float4 component access (folds to .x/.y/.z/.w after unroll).
#define F4E(v,i) ((i)==0?(v).x:((i)==1?(v).y:((i)==2?(v).z:(v).w)))

#define CHUNK 4096      // edges per partition block (512 threads x 8)
#define ITERS 8

__device__ inline float4 shfl4b(float4 v, int src) {
    float4 r;
    r.x = __shfl(v.x, src, 4); r.y = __shfl(v.y, src, 4);
    r.z = __shfl(v.z, src, 4); r.w = __shfl(v.w, src, 4);
    return r;
}
__device__ inline float4 shfl8b(float4 v, int src) {
    float4 r;
    r.x = __shfl(v.x, src, 8); r.y = __shfl(v.y, src, 8);
    r.z = __shfl(v.z, src, 8); r.w = __shfl(v.w, src, 8);
    return r;
}

// fp32 -> bf16 (RNE) pack of two values into one uint (lo = a, hi = b).
__device__ inline unsigned packbf2(float a, float b) {
    unsigned ua = __float_as_uint(a), ub = __float_as_uint(b);
    ua = (ua + 0x7fffu + ((ua >> 16) & 1u)) >> 16;
    ub = (ub + 0x7fffu + ((ub >> 16) & 1u)) >> 16;
    return ua | (ub << 16);
}
// bf16 pair (one uint) -> two floats.
__device__ inline float bflo(unsigned w) { return __uint_as_float(w << 16); }
__device__ inline float bfhi(unsigned w) { return __uint_as_float(w & 0xffff0000u); }

// ---------------------------------------------------------------------------
// Convert x (N x 16 fp32) -> xb (N x 16 bf16). 8 elements per thread.
// 3.2 MB result fits a single XCD L2 -> layer-1 gather becomes L2-resident.
__global__ __launch_bounds__(256) void k_xcvt(
    const float* __restrict__ x, unsigned short* __restrict__ xb, int n8)
{
    int i = blockIdx.x * 256 + threadIdx.x;
    if (i >= n8) return;
    const float4* xp = reinterpret_cast<const float4*>(x) + (size_t)i * 2;
    float4 a = xp[0], b = xp[1];
    uint4 w;
    w.x = packbf2(a.x, a.y); w.y = packbf2(a.z, a.w);
    w.z = packbf2(b.x, b.y); w.w = packbf2(b.z, b.w);
    reinterpret_cast<uint4*>(xb)[i] = w;
}

// ---------------------------------------------------------------------------
// Bucket histogram: bucket = dst >> 8 (256 nodes per bucket), NB <= 512.
__global__ __launch_bounds__(512) void k_bhist(
    const int* __restrict__ ei, int* __restrict__ bhist, int E, int NB)
{
    __shared__ int cnt[512];
    int t = threadIdx.x;
    cnt[t] = 0;
    __syncthreads();
    int base = blockIdx.x * CHUNK;
#pragma unroll
    for (int i = 0; i < ITERS; ++i) {
        int e = base + i * 512 + t;
        if (e < E) {
            int dst = ei[E + e];
            atomicAdd(&cnt[dst >> 8], 1);
        }
    }
    __syncthreads();
    if (t < NB && cnt[t]) atomicAdd(&bhist[t], cnt[t]);
}

// Exclusive scan of bucket counts (NB <= 512), writes bstart + cursor init.
__global__ __launch_bounds__(512) void k_bscan(
    const int* __restrict__ bhist, int* __restrict__ bstart,
    int* __restrict__ gcursor, int NB, int E)
{
    __shared__ int s[512];
    int t = threadIdx.x;
    int v0 = (t < NB) ? bhist[t] : 0;
    s[t] = v0;
    __syncthreads();
    for (int off = 1; off < 512; off <<= 1) {
        int v = (t >= off) ? s[t - off] : 0;
        __syncthreads();
        s[t] += v;
        __syncthreads();
    }
    if (t < NB) { int ex = s[t] - v0; bstart[t] = ex; gcursor[t] = ex; }
    if (t == 0) bstart[NB] = E;
}

// Partition edges into bucket-contiguous packed list, coalesced flush.
// packed = (src << 8) | (dst & 255); requires N < 2^17 (holds: 100000).
__global__ __launch_bounds__(512) void k_partition(
    const int* __restrict__ ei, int* __restrict__ gcursor,
    int* __restrict__ epack, int E)
{
    __shared__ int cnt[512], sc[512], lbase[512], gbase[512], lcnt[512];
    __shared__ int stage[CHUNK];
    __shared__ unsigned short stageb[CHUNK];
    int t = threadIdx.x;
    cnt[t] = 0; lcnt[t] = 0;
    __syncthreads();

    int base = blockIdx.x * CHUNK;
    int pk[ITERS], bb[ITERS];
#pragma unroll
    for (int i = 0; i < ITERS; ++i) {
        int e = base + i * 512 + t;
        if (e < E) {
            int src = ei[e], dst = ei[E + e];
            pk[i] = (src << 8) | (dst & 255);
            bb[i] = dst >> 8;
            atomicAdd(&cnt[bb[i]], 1);
        } else bb[i] = -1;
    }
    __syncthreads();

    int v0 = cnt[t];
    sc[t] = v0;
    __syncthreads();
    for (int off = 1; off < 512; off <<= 1) {
        int v = (t >= off) ? sc[t - off] : 0;
        __syncthreads();
        sc[t] += v;
        __syncthreads();
    }
    lbase[t] = sc[t] - v0;
    if (v0 > 0) gbase[t] = atomicAdd(&gcursor[t], v0);
    __syncthreads();

#pragma unroll
    for (int i = 0; i < ITERS; ++i) {
        if (bb[i] >= 0) {
            int loc = atomicAdd(&lcnt[bb[i]], 1);
            int slot = lbase[bb[i]] + loc;
            stage[slot] = pk[i];
            stageb[slot] = (unsigned short)bb[i];
        }
    }
    __syncthreads();

    int m = min(CHUNK, E - base);
#pragma unroll
    for (int i = 0; i < ITERS; ++i) {
        int slot = i * 512 + t;
        if (slot < m) {
            int b = stageb[slot];
            epack[gbase[b] + (slot - lbase[b])] = stage[slot];
        }
    }
}

// ---------------------------------------------------------------------------
// Per-bucket counting sort by dst&255 -> per-node CSR (rs + esorted of src).
__global__ __launch_bounds__(256) void k_sort(
    const int* __restrict__ bstart, const int* __restrict__ epack,
    int* __restrict__ rs, int* __restrict__ esorted, int N, int E)
{
    __shared__ int hist[256], cur[256], sc[256];
    int t = threadIdx.x;
    int b = blockIdx.x;
    int s0 = bstart[b], s1 = bstart[b + 1];
    hist[t] = 0;
    __syncthreads();
    for (int e = s0 + t; e < s1; e += 256)
        atomicAdd(&hist[epack[e] & 255], 1);
    __syncthreads();

    int v0 = hist[t];
    sc[t] = v0;
    __syncthreads();
    for (int off = 1; off < 256; off <<= 1) {
        int v = (t >= off) ? sc[t - off] : 0;
        __syncthreads();
        sc[t] += v;
        __syncthreads();
    }
    int excl = sc[t] - v0;
    cur[t] = excl;
    int node = (b << 8) + t;
    if (node < N) rs[node] = s0 + excl;
    if (b == 0 && t == 0) rs[N] = E;
    __syncthreads();

    for (int e = s0 + t; e < s1; e += 256) {
        int pk = epack[e];
        int dlo = pk & 255;
        int pos = s0 + atomicAdd(&cur[dlo], 1);
        esorted[pos] = ((unsigned)pk) >> 8;
    }
}

// ---------------------------------------------------------------------------
// Fused gather(F=16, bf16 rows) + layer1: 4 threads per node.
// Gathers from xb (3.2 MB, L2-resident); root term from exact fp32 x.
// Writes h1 as bf16 (RNE).
__global__ __launch_bounds__(256) void k_g1f(
    const float* __restrict__ x, const unsigned short* __restrict__ xb,
    const int* __restrict__ rs, const int* __restrict__ esrc,
    const float* __restrict__ wroot, const float* __restrict__ wrel,
    const float* __restrict__ bias, unsigned short* __restrict__ h1, int N)
{
    __shared__ float4 s_wr[128], s_wl[128], s_b[8];   // 16x32 each, bias 32
    int t = threadIdx.x;
    if (t < 128) {
        s_wr[t] = reinterpret_cast<const float4*>(wroot)[t];
        s_wl[t] = reinterpret_cast<const float4*>(wrel)[t];
    }
    if (t < 8) s_b[t] = reinterpret_cast<const float4*>(bias)[t];
    __syncthreads();

    int tid = blockIdx.x * 256 + t;
    int n = tid >> 2, p = tid & 3;
    if (n >= N) return;
    int s0 = rs[n], s1 = rs[n + 1];
    float4 g = make_float4(0.f, 0.f, 0.f, 0.f);
    int e = s0;
    for (; e + 7 < s1; e += 8) {                   // 8 loads in flight
        uint2 w[8];
#pragma unroll
        for (int u = 0; u < 8; ++u) {
            int src = esrc[e + u];
            w[u] = reinterpret_cast<const uint2*>(xb + (size_t)src * 16)[p];
        }
#pragma unroll
        for (int u = 0; u < 8; ++u) {
            g.x += bflo(w[u].x); g.y += bfhi(w[u].x);
            g.z += bflo(w[u].y); g.w += bfhi(w[u].y);
        }
    }
    for (; e < s1; ++e) {
        int src = esrc[e];
        uint2 w0 = reinterpret_cast<const uint2*>(xb + (size_t)src * 16)[p];
        g.x += bflo(w0.x); g.y += bfhi(w0.x);
        g.z += bflo(w0.y); g.w += bfhi(w0.y);
    }
    float4 a = *reinterpret_cast<const float4*>(x + (size_t)n * 16 + p * 4);

    int jb = p * 2;                          // my 2 float4 columns of 8
    float4 acc0 = s_b[jb], acc1 = s_b[jb + 1];
#pragma unroll
    for (int kc = 0; kc < 4; ++kc) {
        float4 a4 = shfl4b(a, kc);
        float4 g4 = shfl4b(g, kc);
#pragma unroll
        for (int kk = 0; kk < 4; ++kk) {
            float av = F4E(a4, kk), gv = F4E(g4, kk);
            int k = kc * 4 + kk;
            float4 wr0 = s_wr[k * 8 + jb], wr1 = s_wr[k * 8 + jb + 1];
            float4 wl0 = s_wl[k * 8 + jb], wl1 = s_wl[k * 8 + jb + 1];
            acc0.x += av * wr0.x + gv * wl0.x;
            acc0.y += av * wr0.y + gv * wl0.y;
            acc0.z += av * wr0.z + gv * wl0.z;
            acc0.w += av * wr0.w + gv * wl0.w;
            acc1.x += av * wr1.x + gv * wl1.x;
            acc1.y += av * wr1.y + gv * wl1.y;
            acc1.z += av * wr1.z + gv * wl1.z;
            acc1.w += av * wr1.w + gv * wl1.w;
        }
    }
    acc0.x = fmaxf(acc0.x, 0.f); acc0.y = fmaxf(acc0.y, 0.f);
    acc0.z = fmaxf(acc0.z, 0.f); acc0.w = fmaxf(acc0.w, 0.f);
    acc1.x = fmaxf(acc1.x, 0.f); acc1.y = fmaxf(acc1.y, 0.f);
    acc1.z = fmaxf(acc1.z, 0.f); acc1.w = fmaxf(acc1.w, 0.f);

    // pack 8 outputs (j = p*8 .. p*8+8) as bf16 into one 16B store
    uint4 w;
    w.x = packbf2(acc0.x, acc0.y);
    w.y = packbf2(acc0.z, acc0.w);
    w.z = packbf2(acc1.x, acc1.y);
    w.w = packbf2(acc1.z, acc1.w);
    reinterpret_cast<uint4*>(h1 + (size_t)n * 32)[p] = w;
}

// ---------------------------------------------------------------------------
// Fused gather(F=32, bf16 rows) + layer2 + fc1 + fc2: 8 threads per node.
// fc2 weights in LDS as packed bf16 -> 26.0 KB total -> 6 blocks/CU.
__global__ __launch_bounds__(256) void k_g2f(
    const unsigned short* __restrict__ h1, const int* __restrict__ rs,
    const int* __restrict__ esrc,
    const float* __restrict__ wroot, const float* __restrict__ wrel,
    const float* __restrict__ bias,
    const float* __restrict__ f1w, const float* __restrict__ f1b,
    const float* __restrict__ f2w, const float* __restrict__ f2b,
    float* __restrict__ out, int N)
{
    __shared__ float4 s_wr[512], s_wl[512], s_b[16];  // 32x64 weights, bias 64
    __shared__ float4 s_f1[512];                      // 64x32, jc-swizzled
    __shared__ unsigned s_f2u[256];                   // 32x16 as bf16 pairs
    __shared__ float4 s_b1[8];
    __shared__ float  s_b2[16];
    int t = threadIdx.x;
    for (int i = t; i < 512; i += 256) {
        s_wr[i] = reinterpret_cast<const float4*>(wroot)[i];
        s_wl[i] = reinterpret_cast<const float4*>(wrel)[i];
        // swizzle: row k (= i>>3), col jc (= i&7) stored at jc' = (jc + (k>>3)) & 7
        int k = i >> 3, jc = i & 7;
        s_f1[(i & ~7) | ((jc + (k >> 3)) & 7)] = reinterpret_cast<const float4*>(f1w)[i];
    }
    {   // fc2 weights: s_f2u[k2*8 + jp] = bf16 pair (j = 2jp, 2jp+1) of row k2
        int k2 = t >> 3, jp = t & 7;
        s_f2u[t] = packbf2(f2w[k2 * 16 + jp * 2], f2w[k2 * 16 + jp * 2 + 1]);
    }
    if (t < 16) s_b[t]  = reinterpret_cast<const float4*>(bias)[t];
    if (t < 8)  s_b1[t] = reinterpret_cast<const float4*>(f1b)[t];
    if (t < 16) s_b2[t] = f2b[t];
    __syncthreads();

    int tid = blockIdx.x * 256 + t;
    int n = tid >> 3, p = tid & 7;
    if (n >= N) return;

    // gather my 4-feature slice of agg2 from bf16 h1 rows (8B/lane/edge,
    // 8 loads in flight)
    int s0 = rs[n], s1 = rs[n + 1];
    float4 g = make_float4(0.f, 0.f, 0.f, 0.f);
    int e = s0;
    for (; e + 7 < s1; e += 8) {
        uint2 w[8];
#pragma unroll
        for (int u = 0; u < 8; ++u) {
            int src = esrc[e + u];
            w[u] = reinterpret_cast<const uint2*>(h1 + (size_t)src * 32)[p];
        }
#pragma unroll
        for (int u = 0; u < 8; ++u) {
            g.x += bflo(w[u].x); g.y += bfhi(w[u].x);
            g.z += bflo(w[u].y); g.w += bfhi(w[u].y);
        }
    }
    for (; e < s1; ++e) {
        int src = esrc[e];
        uint2 w0 = reinterpret_cast<const uint2*>(h1 + (size_t)src * 32)[p];
        g.x += bflo(w0.x); g.y += bfhi(w0.x);
        g.z += bflo(w0.y); g.w += bfhi(w0.y);
    }
    uint2 aw = reinterpret_cast<const uint2*>(h1 + (size_t)n * 32)[p];
    float4 a = make_float4(bflo(aw.x), bfhi(aw.x), bflo(aw.y), bfhi(aw.y));

    // layer2: my 8 of 64 h2 outputs (j in [p*8, p*8+8)), jb = p*2 float4 cols
    int jb = p * 2;
    float4 acc0 = s_b[jb], acc1 = s_b[jb + 1];
#pragma unroll
    for (int kc = 0; kc < 8; ++kc) {
        float4 a4 = shfl8b(a, kc);
        float4 g4 = shfl8b(g, kc);
#pragma unroll
        for (int kk = 0; kk < 4; ++kk) {
            float av = F4E(a4, kk), gv = F4E(g4, kk);
            int k = kc * 4 + kk;
            float4 wr0 = s_wr[k * 16 + jb], wr1 = s_wr[k * 16 + jb + 1];
            float4 wl0 = s_wl[k * 16 + jb], wl1 = s_wl[k * 16 + jb + 1];
            acc0.x += av * wr0.x + gv * wl0.x;
            acc0.y += av * wr0.y + gv * wl0.y;
            acc0.z += av * wr0.z + gv * wl0.z;
            acc0.w += av * wr0.w + gv * wl0.w;
            acc1.x += av * wr1.x + gv * wl1.x;
            acc1.y += av * wr1.y + gv * wl1.y;
            acc1.z += av * wr1.z + gv * wl1.z;
            acc1.w += av * wr1.w + gv * wl1.w;
        }
    }
    acc0.x = fmaxf(acc0.x, 0.f); acc0.y = fmaxf(acc0.y, 0.f);
    acc0.z = fmaxf(acc0.z, 0.f); acc0.w = fmaxf(acc0.w, 0.f);
    acc1.x = fmaxf(acc1.x, 0.f); acc1.y = fmaxf(acc1.y, 0.f);
    acc1.z = fmaxf(acc1.z, 0.f); acc1.w = fmaxf(acc1.w, 0.f);

    // fc1 k-split: my 8 h2 values are k = p*8 + kk; partials over all 32 outs.
    float4 f[8];
    float4 z4 = make_float4(0.f, 0.f, 0.f, 0.f);
#pragma unroll
    for (int jc = 0; jc < 8; ++jc) f[jc] = p ? z4 : s_b1[jc];
#pragma unroll
    for (int kk = 0; kk < 8; ++kk) {
        float hv = (kk < 4) ? F4E(acc0, kk) : F4E(acc1, kk - 4);
        int k = p * 8 + kk;
        int row = k * 8;
#pragma unroll
        for (int jc = 0; jc < 8; ++jc) {
            float4 w = s_f1[row | ((jc + p) & 7)];
            f[jc].x += hv * w.x; f[jc].y += hv * w.y;
            f[jc].z += hv * w.z; f[jc].w += hv * w.w;
        }
    }
    // butterfly reduce across the 8-lane group + relu
#pragma unroll
    for (int m = 1; m < 8; m <<= 1) {
#pragma unroll
        for (int jc = 0; jc < 8; ++jc) {
            f[jc].x += __shfl_xor(f[jc].x, m);
            f[jc].y += __shfl_xor(f[jc].y, m);
            f[jc].z += __shfl_xor(f[jc].z, m);
            f[jc].w += __shfl_xor(f[jc].w, m);
        }
    }
#pragma unroll
    for (int jc = 0; jc < 8; ++jc) {
        f[jc].x = fmaxf(f[jc].x, 0.f); f[jc].y = fmaxf(f[jc].y, 0.f);
        f[jc].z = fmaxf(f[jc].z, 0.f); f[jc].w = fmaxf(f[jc].w, 0.f);
    }

    // fc2 j-split: my 2 of 16 outputs (j = p*2, p*2+1); weights bf16-packed,
    // lane p's pair is exactly s_f2u[k2*8 + p].
    float o0 = s_b2[p * 2], o1 = s_b2[p * 2 + 1];
#pragma unroll
    for (int k2 = 0; k2 < 32; ++k2) {
        float av = F4E(f[k2 >> 2], k2 & 3);
        unsigned wp = s_f2u[k2 * 8 + p];
        o0 += av * bflo(wp);
        o1 += av * bfhi(wp);
    }
    float2* o = reinterpret_cast<float2*>(out + (size_t)n * 16 + p * 2);
    *o = make_float2(o0, o1);
}

// ---------------------------------------------------------------------------
extern "C" void kernel_launch(void* const* d_in, const int* in_sizes, int n_in,
                              void* d_out, int out_size, void* d_ws, size_t ws_size,
                              hipStream_t stream)
{
    const float* x   = (const float*)d_in[0];
    const int*   ei  = (const int*)d_in[1];
    const float* wr1 = (const float*)d_in[2];
    const float* wl1 = (const float*)d_in[3];
    const float* b1  = (const float*)d_in[4];
    const float* wr2 = (const float*)d_in[5];
    const float* wl2 = (const float*)d_in[6];
    const float* b2  = (const float*)d_in[7];
    const float* f1w = (const float*)d_in[8];
    const float* f1b = (const float*)d_in[9];
    const float* f2w = (const float*)d_in[10];
    const float* f2b = (const float*)d_in[11];
    float* out = (float*)d_out;

    const int N  = in_sizes[0] / 16;
    const int E  = in_sizes[1] / 2;
    const int NB = (N + 255) >> 8;      // 256 nodes per bucket, NB <= 512

    // Workspace layout (no aliasing; ~23MB of >=51.2MB):
    //   h1      : N*32 bf16 (= N*16 float slots)   6.4 MB
    //   xb      : N*16 bf16 (= N*8  float slots)   3.2 MB
    //   esorted : E ints
    //   epack   : E ints
    //   rs      : N+1 ints; bhist/bstart/gcursor tiny
    float*          ws      = (float*)d_ws;
    unsigned short* h1      = (unsigned short*)ws;
    unsigned short* xb      = (unsigned short*)(ws + (size_t)N * 16);
    int*            esorted = (int*)(ws + (size_t)N * 24);
    int*            epack   = esorted + E;
    int*            rs      = epack + E;
    int*            bhist   = rs + N + 1;
    int*            bstart  = bhist + NB;
    int*            gcursor = bstart + NB + 1;

    hipMemsetAsync(bhist, 0, (size_t)NB * sizeof(int), stream);

    int nchunk = (E + CHUNK - 1) / CHUNK;
    int g_cv = (N * 2 + 255) / 256;
    int g_g1 = (N * 4 + 255) / 256;
    int g_g2 = (N * 8 + 255) / 256;

    k_xcvt     <<<g_cv,   256, 0, stream>>>(x, xb, N * 2);
    k_bhist    <<<nchunk, 512, 0, stream>>>(ei, bhist, E, NB);
    k_bscan    <<<1,      512, 0, stream>>>(bhist, bstart, gcursor, NB, E);
    k_partition<<<nchunk, 512, 0, stream>>>(ei, gcursor, epack, E);
    k_sort     <<<NB,     256, 0, stream>>>(bstart, epack, rs, esorted, N, E);

    k_g1f      <<<g_g1, 256, 0, stream>>>(x, xb, rs, esorted, wr1, wl1, b1, h1, N);
    k_g2f      <<<g_g2, 256, 0, stream>>>(h1, rs, esorted, wr2, wl2, b2,
                                          f1w, f1b, f2w, f2b, out, N);
}

// Round 13
// 197.699 us; speedup vs baseline: 4.0474x; 1.0919x over previous
//
#include <hip/hip_runtime.h>

// Static float4 component access (folds to .x/.y/.z/.w after unroll).
#define F4E(v,i) ((i)==0?(v).x:((i)==1?(v).y:((i)==2?(v).z:(v).w)))

#define CHUNK 4096      // edges per partition block (512 threads x 8)
#define ITERS 8

typedef __attribute__((ext_vector_type(8))) short short8;   // 8 bf16 (4 VGPR)
typedef __attribute__((ext_vector_type(4))) float f32x4;    // mfma acc

__device__ inline float4 shfl4b(float4 v, int src) {
    float4 r;
    r.x = __shfl(v.x, src, 4); r.y = __shfl(v.y, src, 4);
    r.z = __shfl(v.z, src, 4); r.w = __shfl(v.w, src, 4);
    return r;
}

// fp32 -> bf16 (RNE) pack of two values into one uint (lo = a, hi = b).
__device__ inline unsigned packbf2(float a, float b) {
    unsigned ua = __float_as_uint(a), ub = __float_as_uint(b);
    ua = (ua + 0x7fffu + ((ua >> 16) & 1u)) >> 16;
    ub = (ub + 0x7fffu + ((ub >> 16) & 1u)) >> 16;
    return ua | (ub << 16);
}
// fp32 -> bf16 bits (RNE)
__device__ inline unsigned short bf16r(float f) {
    unsigned u = __float_as_uint(f);
    return (unsigned short)((u + 0x7fffu + ((u >> 16) & 1u)) >> 16);
}
// bf16 pair (one uint) -> two floats.
__device__ inline float bflo(unsigned w) { return __uint_as_float(w << 16); }
__device__ inline float bfhi(unsigned w) { return __uint_as_float(w & 0xffff0000u); }

// ---------------------------------------------------------------------------
// Convert x (N x 16 fp32) -> xb (N x 16 bf16). 8 elements per thread.
__global__ __launch_bounds__(256) void k_xcvt(
    const float* __restrict__ x, unsigned short* __restrict__ xb, int n8)
{
    int i = blockIdx.x * 256 + threadIdx.x;
    if (i >= n8) return;
    const float4* xp = reinterpret_cast<const float4*>(x) + (size_t)i * 2;
    float4 a = xp[0], b = xp[1];
    uint4 w;
    w.x = packbf2(a.x, a.y); w.y = packbf2(a.z, a.w);
    w.z = packbf2(b.x, b.y); w.w = packbf2(b.z, b.w);
    reinterpret_cast<uint4*>(xb)[i] = w;
}

// ---------------------------------------------------------------------------
// Bucket histogram: bucket = dst >> 8 (256 nodes per bucket), NB <= 512.
__global__ __launch_bounds__(512) void k_bhist(
    const int* __restrict__ ei, int* __restrict__ bhist, int E, int NB)
{
    __shared__ int cnt[512];
    int t = threadIdx.x;
    cnt[t] = 0;
    __syncthreads();
    int base = blockIdx.x * CHUNK;
#pragma unroll
    for (int i = 0; i < ITERS; ++i) {
        int e = base + i * 512 + t;
        if (e < E) {
            int dst = ei[E + e];
            atomicAdd(&cnt[dst >> 8], 1);
        }
    }
    __syncthreads();
    if (t < NB && cnt[t]) atomicAdd(&bhist[t], cnt[t]);
}

// Exclusive scan of bucket counts (NB <= 512), writes bstart + cursor init.
__global__ __launch_bounds__(512) void k_bscan(
    const int* __restrict__ bhist, int* __restrict__ bstart,
    int* __restrict__ gcursor, int NB, int E)
{
    __shared__ int s[512];
    int t = threadIdx.x;
    int v0 = (t < NB) ? bhist[t] : 0;
    s[t] = v0;
    __syncthreads();
    for (int off = 1; off < 512; off <<= 1) {
        int v = (t >= off) ? s[t - off] : 0;
        __syncthreads();
        s[t] += v;
        __syncthreads();
    }
    if (t < NB) { int ex = s[t] - v0; bstart[t] = ex; gcursor[t] = ex; }
    if (t == 0) bstart[NB] = E;
}

// Partition edges into bucket-contiguous packed list, coalesced flush.
// packed = (src << 8) | (dst & 255); requires N < 2^17 (holds: 100000).
__global__ __launch_bounds__(512) void k_partition(
    const int* __restrict__ ei, int* __restrict__ gcursor,
    int* __restrict__ epack, int E)
{
    __shared__ int cnt[512], sc[512], lbase[512], gbase[512], lcnt[512];
    __shared__ int stage[CHUNK];
    __shared__ unsigned short stageb[CHUNK];
    int t = threadIdx.x;
    cnt[t] = 0; lcnt[t] = 0;
    __syncthreads();

    int base = blockIdx.x * CHUNK;
    int pk[ITERS], bb[ITERS];
#pragma unroll
    for (int i = 0; i < ITERS; ++i) {
        int e = base + i * 512 + t;
        if (e < E) {
            int src = ei[e], dst = ei[E + e];
            pk[i] = (src << 8) | (dst & 255);
            bb[i] = dst >> 8;
            atomicAdd(&cnt[bb[i]], 1);
        } else bb[i] = -1;
    }
    __syncthreads();

    int v0 = cnt[t];
    sc[t] = v0;
    __syncthreads();
    for (int off = 1; off < 512; off <<= 1) {
        int v = (t >= off) ? sc[t - off] : 0;
        __syncthreads();
        sc[t] += v;
        __syncthreads();
    }
    lbase[t] = sc[t] - v0;
    if (v0 > 0) gbase[t] = atomicAdd(&gcursor[t], v0);
    __syncthreads();

#pragma unroll
    for (int i = 0; i < ITERS; ++i) {
        if (bb[i] >= 0) {
            int loc = atomicAdd(&lcnt[bb[i]], 1);
            int slot = lbase[bb[i]] + loc;
            stage[slot] = pk[i];
            stageb[slot] = (unsigned short)bb[i];
        }
    }
    __syncthreads();

    int m = min(CHUNK, E - base);
#pragma unroll
    for (int i = 0; i < ITERS; ++i) {
        int slot = i * 512 + t;
        if (slot < m) {
            int b = stageb[slot];
            epack[gbase[b] + (slot - lbase[b])] = stage[slot];
        }
    }
}

// ---------------------------------------------------------------------------
// Per-bucket counting sort by dst&255 -> per-node CSR (rs + esorted of src).
__global__ __launch_bounds__(256) void k_sort(
    const int* __restrict__ bstart, const int* __restrict__ epack,
    int* __restrict__ rs, int* __restrict__ esorted, int N, int E)
{
    __shared__ int hist[256], cur[256], sc[256];
    int t = threadIdx.x;
    int b = blockIdx.x;
    int s0 = bstart[b], s1 = bstart[b + 1];
    hist[t] = 0;
    __syncthreads();
    for (int e = s0 + t; e < s1; e += 256)
        atomicAdd(&hist[epack[e] & 255], 1);
    __syncthreads();

    int v0 = hist[t];
    sc[t] = v0;
    __syncthreads();
    for (int off = 1; off < 256; off <<= 1) {
        int v = (t >= off) ? sc[t - off] : 0;
        __syncthreads();
        sc[t] += v;
        __syncthreads();
    }
    int excl = sc[t] - v0;
    cur[t] = excl;
    int node = (b << 8) + t;
    if (node < N) rs[node] = s0 + excl;
    if (b == 0 && t == 0) rs[N] = E;
    __syncthreads();

    for (int e = s0 + t; e < s1; e += 256) {
        int pk = epack[e];
        int dlo = pk & 255;
        int pos = s0 + atomicAdd(&cur[dlo], 1);
        esorted[pos] = ((unsigned)pk) >> 8;
    }
}

// ---------------------------------------------------------------------------
// Fused gather(F=16, bf16 rows) + layer1: 4 threads per node (round-12 form).
__global__ __launch_bounds__(256) void k_g1f(
    const float* __restrict__ x, const unsigned short* __restrict__ xb,
    const int* __restrict__ rs, const int* __restrict__ esrc,
    const float* __restrict__ wroot, const float* __restrict__ wrel,
    const float* __restrict__ bias, unsigned short* __restrict__ h1, int N)
{
    __shared__ float4 s_wr[128], s_wl[128], s_b[8];   // 16x32 each, bias 32
    int t = threadIdx.x;
    if (t < 128) {
        s_wr[t] = reinterpret_cast<const float4*>(wroot)[t];
        s_wl[t] = reinterpret_cast<const float4*>(wrel)[t];
    }
    if (t < 8) s_b[t] = reinterpret_cast<const float4*>(bias)[t];
    __syncthreads();

    int tid = blockIdx.x * 256 + t;
    int n = tid >> 2, p = tid & 3;
    if (n >= N) return;
    int s0 = rs[n], s1 = rs[n + 1];
    float4 g = make_float4(0.f, 0.f, 0.f, 0.f);
    int e = s0;
    for (; e + 7 < s1; e += 8) {                   // 8 loads in flight
        uint2 w[8];
#pragma unroll
        for (int u = 0; u < 8; ++u) {
            int src = esrc[e + u];
            w[u] = reinterpret_cast<const uint2*>(xb + (size_t)src * 16)[p];
        }
#pragma unroll
        for (int u = 0; u < 8; ++u) {
            g.x += bflo(w[u].x); g.y += bfhi(w[u].x);
            g.z += bflo(w[u].y); g.w += bfhi(w[u].y);
        }
    }
    for (; e < s1; ++e) {
        int src = esrc[e];
        uint2 w0 = reinterpret_cast<const uint2*>(xb + (size_t)src * 16)[p];
        g.x += bflo(w0.x); g.y += bfhi(w0.x);
        g.z += bflo(w0.y); g.w += bfhi(w0.y);
    }
    float4 a = *reinterpret_cast<const float4*>(x + (size_t)n * 16 + p * 4);

    int jb = p * 2;                          // my 2 float4 columns of 8
    float4 acc0 = s_b[jb], acc1 = s_b[jb + 1];
#pragma unroll
    for (int kc = 0; kc < 4; ++kc) {
        float4 a4 = shfl4b(a, kc);
        float4 g4 = shfl4b(g, kc);
#pragma unroll
        for (int kk = 0; kk < 4; ++kk) {
            float av = F4E(a4, kk), gv = F4E(g4, kk);
            int k = kc * 4 + kk;
            float4 wr0 = s_wr[k * 8 + jb], wr1 = s_wr[k * 8 + jb + 1];
            float4 wl0 = s_wl[k * 8 + jb], wl1 = s_wl[k * 8 + jb + 1];
            acc0.x += av * wr0.x + gv * wl0.x;
            acc0.y += av * wr0.y + gv * wl0.y;
            acc0.z += av * wr0.z + gv * wl0.z;
            acc0.w += av * wr0.w + gv * wl0.w;
            acc1.x += av * wr1.x + gv * wl1.x;
            acc1.y += av * wr1.y + gv * wl1.y;
            acc1.z += av * wr1.z + gv * wl1.z;
            acc1.w += av * wr1.w + gv * wl1.w;
        }
    }
    acc0.x = fmaxf(acc0.x, 0.f); acc0.y = fmaxf(acc0.y, 0.f);
    acc0.z = fmaxf(acc0.z, 0.f); acc0.w = fmaxf(acc0.w, 0.f);
    acc1.x = fmaxf(acc1.x, 0.f); acc1.y = fmaxf(acc1.y, 0.f);
    acc1.z = fmaxf(acc1.z, 0.f); acc1.w = fmaxf(acc1.w, 0.f);

    uint4 w;
    w.x = packbf2(acc0.x, acc0.y);
    w.y = packbf2(acc0.z, acc0.w);
    w.z = packbf2(acc1.x, acc1.y);
    w.w = packbf2(acc1.z, acc1.w);
    reinterpret_cast<uint4*>(h1 + (size_t)n * 32)[p] = w;
}

// ---------------------------------------------------------------------------
// MFMA-based fused gather + layer2 + fc1 + fc2.
// One wave = one 16-node tile. Fragment mapping (verified, guide §3):
//   A[m][k]: m = lane&15, k = (lane>>4)*8 + i
//   B[k][j]: j = lane&15, k = (lane>>4)*8 + i
//   D[m][j]: j = lane&15, m = (lane>>4)*4 + r
// Weights live in VGPRs as bf16 fragments; h2/f re-shaped via per-wave LDS.
__global__ __launch_bounds__(256) void k_g2f(
    const unsigned short* __restrict__ h1, const int* __restrict__ rs,
    const int* __restrict__ esrc,
    const float* __restrict__ wroot, const float* __restrict__ wrel,
    const float* __restrict__ bias,
    const float* __restrict__ f1w, const float* __restrict__ f1b,
    const float* __restrict__ f2w, const float* __restrict__ f2b,
    float* __restrict__ out, int N)
{
    __shared__ __attribute__((aligned(16))) unsigned short h2l[4][16][72]; // 64+8 pad
    __shared__ __attribute__((aligned(16))) unsigned short fl[4][16][40];  // 32+8 pad

    int t = threadIdx.x;
    int w = t >> 6, l = t & 63;
    int m = l & 15, q4 = l >> 4;
    int tile = blockIdx.x * 4 + w;
    int nb = tile * 16;
    if (nb >= N) return;

    // ---- weight fragments (VGPR-resident bf16) ----
    short8 fwr[4], fwl[4];
#pragma unroll
    for (int nt = 0; nt < 4; ++nt) {
#pragma unroll
        for (int i = 0; i < 8; ++i) {
            int k = q4 * 8 + i, j = nt * 16 + m;
            fwr[nt][i] = (short)bf16r(wroot[k * 64 + j]);
            fwl[nt][i] = (short)bf16r(wrel[k * 64 + j]);
        }
    }
    short8 ff1[2][2];
#pragma unroll
    for (int ks = 0; ks < 2; ++ks)
#pragma unroll
        for (int nt = 0; nt < 2; ++nt)
#pragma unroll
            for (int i = 0; i < 8; ++i)
                ff1[ks][nt][i] = (short)bf16r(f1w[(ks * 32 + q4 * 8 + i) * 32 + nt * 16 + m]);
    short8 ff2;
#pragma unroll
    for (int i = 0; i < 8; ++i)
        ff2[i] = (short)bf16r(f2w[(q4 * 8 + i) * 16 + m]);

    // ---- gather: node nb+m, features q4*8..+8 of agg2 from bf16 h1 rows ----
    int n = nb + m;
    int s0 = 0, s1 = 0;
    if (n < N) { s0 = rs[n]; s1 = rs[n + 1]; }
    float ga0 = 0, ga1 = 0, ga2 = 0, ga3 = 0, ga4 = 0, ga5 = 0, ga6 = 0, ga7 = 0;
#define ACC8(W) { ga0 += bflo((W).x); ga1 += bfhi((W).x); \
                  ga2 += bflo((W).y); ga3 += bfhi((W).y); \
                  ga4 += bflo((W).z); ga5 += bfhi((W).z); \
                  ga6 += bflo((W).w); ga7 += bfhi((W).w); }
    int e = s0;
    for (; e + 3 < s1; e += 4) {                     // 4 row-loads in flight
        int sa = esrc[e], sb = esrc[e + 1], sc2 = esrc[e + 2], sd = esrc[e + 3];
        uint4 wa = *reinterpret_cast<const uint4*>(h1 + (size_t)sa * 32 + q4 * 8);
        uint4 wb = *reinterpret_cast<const uint4*>(h1 + (size_t)sb * 32 + q4 * 8);
        uint4 wc = *reinterpret_cast<const uint4*>(h1 + (size_t)sc2 * 32 + q4 * 8);
        uint4 wd = *reinterpret_cast<const uint4*>(h1 + (size_t)sd * 32 + q4 * 8);
        ACC8(wa) ACC8(wb) ACC8(wc) ACC8(wd)
    }
    for (; e < s1; ++e) {
        int sa = esrc[e];
        uint4 wa = *reinterpret_cast<const uint4*>(h1 + (size_t)sa * 32 + q4 * 8);
        ACC8(wa)
    }
#undef ACC8

    // a-frag: self row (already bf16); g-frag: pack gathered sums.
    short8 af;
    {
        uint4 av = make_uint4(0, 0, 0, 0);
        if (n < N) av = *reinterpret_cast<const uint4*>(h1 + (size_t)n * 32 + q4 * 8);
        __builtin_memcpy(&af, &av, 16);
    }
    short8 gf;
    gf[0] = (short)bf16r(ga0); gf[1] = (short)bf16r(ga1);
    gf[2] = (short)bf16r(ga2); gf[3] = (short)bf16r(ga3);
    gf[4] = (short)bf16r(ga4); gf[5] = (short)bf16r(ga5);
    gf[6] = (short)bf16r(ga6); gf[7] = (short)bf16r(ga7);

    // ---- layer2: h2 = a@Wroot + g@Wrel + b  (8 mfma) ----
    f32x4 acc[4];
#pragma unroll
    for (int nt = 0; nt < 4; ++nt) {
        float bj = bias[nt * 16 + m];
        acc[nt] = (f32x4){bj, bj, bj, bj};
        acc[nt] = __builtin_amdgcn_mfma_f32_16x16x32_bf16(af, fwr[nt], acc[nt], 0, 0, 0);
        acc[nt] = __builtin_amdgcn_mfma_f32_16x16x32_bf16(gf, fwl[nt], acc[nt], 0, 0, 0);
    }
    // relu + bounce to LDS (D layout -> A layout)
#pragma unroll
    for (int nt = 0; nt < 4; ++nt)
#pragma unroll
        for (int r = 0; r < 4; ++r)
            h2l[w][q4 * 4 + r][nt * 16 + m] = bf16r(fmaxf(acc[nt][r], 0.f));

    short8 h2a[2];
#pragma unroll
    for (int ks = 0; ks < 2; ++ks) {
        uint4 v = *reinterpret_cast<const uint4*>(&h2l[w][m][ks * 32 + q4 * 8]);
        __builtin_memcpy(&h2a[ks], &v, 16);
    }

    // ---- fc1 (4 mfma) ----
    f32x4 fa[2];
#pragma unroll
    for (int nt = 0; nt < 2; ++nt) {
        float bj = f1b[nt * 16 + m];
        fa[nt] = (f32x4){bj, bj, bj, bj};
        fa[nt] = __builtin_amdgcn_mfma_f32_16x16x32_bf16(h2a[0], ff1[0][nt], fa[nt], 0, 0, 0);
        fa[nt] = __builtin_amdgcn_mfma_f32_16x16x32_bf16(h2a[1], ff1[1][nt], fa[nt], 0, 0, 0);
    }
#pragma unroll
    for (int nt = 0; nt < 2; ++nt)
#pragma unroll
        for (int r = 0; r < 4; ++r)
            fl[w][q4 * 4 + r][nt * 16 + m] = bf16r(fmaxf(fa[nt][r], 0.f));

    short8 ffr;
    {
        uint4 v = *reinterpret_cast<const uint4*>(&fl[w][m][q4 * 8]);
        __builtin_memcpy(&ffr, &v, 16);
    }

    // ---- fc2 (1 mfma) + store ----
    float bj2 = f2b[m];
    f32x4 oacc = (f32x4){bj2, bj2, bj2, bj2};
    oacc = __builtin_amdgcn_mfma_f32_16x16x32_bf16(ffr, ff2, oacc, 0, 0, 0);
#pragma unroll
    for (int r = 0; r < 4; ++r) {
        int node = nb + q4 * 4 + r;
        if (node < N) out[(size_t)node * 16 + m] = oacc[r];
    }
}

// ---------------------------------------------------------------------------
extern "C" void kernel_launch(void* const* d_in, const int* in_sizes, int n_in,
                              void* d_out, int out_size, void* d_ws, size_t ws_size,
                              hipStream_t stream)
{
    const float* x   = (const float*)d_in[0];
    const int*   ei  = (const int*)d_in[1];
    const float* wr1 = (const float*)d_in[2];
    const float* wl1 = (const float*)d_in[3];
    const float* b1  = (const float*)d_in[4];
    const float* wr2 = (const float*)d_in[5];
    const float* wl2 = (const float*)d_in[6];
    const float* b2  = (const float*)d_in[7];
    const float* f1w = (const float*)d_in[8];
    const float* f1b = (const float*)d_in[9];
    const float* f2w = (const float*)d_in[10];
    const float* f2b = (const float*)d_in[11];
    float* out = (float*)d_out;

    const int N  = in_sizes[0] / 16;
    const int E  = in_sizes[1] / 2;
    const int NB = (N + 255) >> 8;      // 256 nodes per bucket, NB <= 512

    // Workspace layout (no aliasing; ~23MB of >=51.2MB):
    //   h1      : N*32 bf16 (= N*16 float slots)   6.4 MB
    //   xb      : N*16 bf16 (= N*8  float slots)   3.2 MB
    //   esorted : E ints
    //   epack   : E ints
    //   rs      : N+1 ints; bhist/bstart/gcursor tiny
    float*          ws      = (float*)d_ws;
    unsigned short* h1      = (unsigned short*)ws;
    unsigned short* xb      = (unsigned short*)(ws + (size_t)N * 16);
    int*            esorted = (int*)(ws + (size_t)N * 24);
    int*            epack   = esorted + E;
    int*            rs      = epack + E;
    int*            bhist   = rs + N + 1;
    int*            bstart  = bhist + NB;
    int*            gcursor = bstart + NB + 1;

    hipMemsetAsync(bhist, 0, (size_t)NB * sizeof(int), stream);

    int nchunk = (E + CHUNK - 1) / CHUNK;
    int g_cv = (N * 2 + 255) / 256;
    int g_g1 = (N * 4 + 255) / 256;
    int g_g2 = (N + 63) / 64;           // 4 waves/block, 16 nodes/wave

    k_xcvt     <<<g_cv,   256, 0, stream>>>(x, xb, N * 2);
    k_bhist    <<<nchunk, 512, 0, stream>>>(ei, bhist, E, NB);
    k_bscan    <<<1,      512, 0, stream>>>(bhist, bstart, gcursor, NB, E);
    k_partition<<<nchunk, 512, 0, stream>>>(ei, gcursor, epack, E);
    k_sort     <<<NB,     256, 0, stream>>>(bstart, epack, rs, esorted, N, E);

    k_g1f      <<<g_g1, 256, 0, stream>>>(x, xb, rs, esorted, wr1, wl1, b1, h1, N);
    k_g2f      <<<g_g2, 256, 0, stream>>>(h1, rs, esorted, wr2, wl2, b2,
                                          f1w, f1b, f2w, f2b, out, N);
}